// Round 1
// 1685.916 us; speedup vs baseline: 1.1115x; 1.1115x over previous
//
#include <hip/hip_runtime.h>
#include <hip/hip_bf16.h>

#define B_   8
#define T_   12
#define CIN  16
#define HD   96
#define COUT 8
#define CE   112
#define CD   104
#define HW   4096
#define WIMG 64

typedef __hip_bfloat16 bf16;
typedef __attribute__((ext_vector_type(8))) short bf16x8;   // 8 bf16 (4 VGPRs)
typedef __attribute__((ext_vector_type(16))) float f32x16;  // MFMA 32x32 C/D

__device__ __forceinline__ float b2f(bf16 v) { return __bfloat162float(v); }
__device__ __forceinline__ float sigmf_(float x) { return 1.0f / (1.0f + __expf(-x)); }
__device__ __forceinline__ float tanhf_(float x) { return 2.0f / (1.0f + __expf(-2.0f * x)) - 1.0f; }

__device__ __forceinline__ float ldin(const void* p, long i, int f32) {
    return f32 ? ((const float*)p)[i] : b2f(((const bf16*)p)[i]);
}
__device__ __forceinline__ short f2bs(float v) {
    __hip_bfloat16 hv = __float2bfloat16(v);
    return *reinterpret_cast<short*>(&hv);
}

// ---------------------------------------------------------------------------
// device-coherent 16B access as 2x 8B agent-scope atomics (bypass L1/L2 via
// sc0 sc1 -> served at the coherent point). This removes the need for any
// cache-invalidating fence at the grid barrier: weights stay L2-resident
// across recurrent steps.
// ---------------------------------------------------------------------------
__device__ __forceinline__ int4 ld_coh16(const short* p) {
    const unsigned long long* q = (const unsigned long long*)p;
    unsigned long long a = __hip_atomic_load(q,     __ATOMIC_RELAXED, __HIP_MEMORY_SCOPE_AGENT);
    unsigned long long c = __hip_atomic_load(q + 1, __ATOMIC_RELAXED, __HIP_MEMORY_SCOPE_AGENT);
    int4 r;
    ((unsigned long long*)&r)[0] = a;
    ((unsigned long long*)&r)[1] = c;
    return r;
}
__device__ __forceinline__ void st_coh16(short* p, int4 v) {
    unsigned long long* q = (unsigned long long*)p;
    __hip_atomic_store(q,     ((unsigned long long*)&v)[0], __ATOMIC_RELAXED, __HIP_MEMORY_SCOPE_AGENT);
    __hip_atomic_store(q + 1, ((unsigned long long*)&v)[1], __ATOMIC_RELAXED, __HIP_MEMORY_SCOPE_AGENT);
}

// ---------------------------------------------------------------------------
// manual grid barrier: monotonic arrival counter, device-scope atomics.
// Safe by capacity: grid=256 blocks, 1 block/CU min occupancy -> all resident.
// NO threadfence: all cross-block payload (h exchange) is done with
// agent-scope coherent loads/stores, so no cache invalidate is required.
// The explicit vmcnt drain + s_barrier guarantees the coherent stores have
// reached the coherence point before the arrival increment.
// ---------------------------------------------------------------------------
__device__ __forceinline__ void gridbar(int* bar, int target) {
    asm volatile("s_waitcnt vmcnt(0)" ::: "memory");   // drain coherent publishes
    __syncthreads();
    if (threadIdx.x == 0) {
        atomicAdd(bar, 1);                             // device-scope arrival
        while (__hip_atomic_load(bar, __ATOMIC_RELAXED,
                                 __HIP_MEMORY_SCOPE_AGENT) < target)
            __builtin_amdgcn_s_sleep(2);
    }
    __syncthreads();
}

// ---------------------------------------------------------------------------
// detect: fp32 vs bf16 input dtype; also zero the grid barrier counter
// ---------------------------------------------------------------------------
__global__ void detect_k(const void* w, int* flag, int* bar) {
    if (threadIdx.x == 0 && blockIdx.x == 0) {
        const unsigned short* u = (const unsigned short*)w;
        int bad = 0;
        for (int i = 0; i < 64; i++) {
            unsigned short v = u[i];
            unsigned e = (v >> 7) & 0xFF;
            if (!(v == 0 || (e >= 90 && e <= 128))) bad++;
        }
        *flag = (bad > 8) ? 1 : 0;
        *bar = 0;
    }
}

// ---------------------------------------------------------------------------
// prep: convert all recurrent-loop weights (bf16 or fp32) -> fp32 workspace
// ---------------------------------------------------------------------------
__global__ void prep_k(
    const void* p0, const void* p1, const void* p2, const void* p3,
    const void* p4, const void* p5, const void* p6, const void* p7,
    const void* p8, const void* p9, const void* p10, const void* p11,
    const void* p12, const void* p13, const void* p14, const void* p15,
    float* __restrict__ dst, const int* __restrict__ flag)
{
    const int f32 = *flag;
    const void* srcs[16] = {p0,p1,p2,p3,p4,p5,p6,p7,p8,p9,p10,p11,p12,p13,p14,p15};
    const int sizes[16] = {10752,10752,10752,10752, 96,96,96,96,
                           89856,89856,89856, 96,96,96, 9984, 96};
    int i = blockIdx.x * blockDim.x + threadIdx.x;
    float* d = dst;
    #pragma unroll 1
    for (int s = 0; s < 16; s++) {
        if (i < sizes[s]) { d[i] = ldin(srcs[s], i, f32); return; }
        i -= sizes[s];
        d += sizes[s];
    }
}

// ---------------------------------------------------------------------------
// combine: fold output head conv(oK)+ob then linear(lW)+lb into one conv
// ---------------------------------------------------------------------------
__global__ void combine_k(const void* __restrict__ oK, const void* __restrict__ obv,
                          const void* __restrict__ lW, const void* __restrict__ lb,
                          float* __restrict__ K2, float* __restrict__ b2,
                          const int* __restrict__ flag)
{
    const int f32 = *flag;
    int i = blockIdx.x * blockDim.x + threadIdx.x;
    if (i < HD * 9) {
        float acc[8] = {0,0,0,0,0,0,0,0};
        for (int cd = 0; cd < CD; cd++) {
            float kv = ldin(oK, cd * (HD * 9) + i, f32);
            #pragma unroll
            for (int o = 0; o < 8; o++)
                acc[o] = fmaf(kv, ldin(lW, cd * COUT + o, f32), acc[o]);
        }
        #pragma unroll
        for (int o = 0; o < 8; o++) K2[i * 8 + o] = acc[o];
    }
    if (i < COUT) {
        float a = ldin(lb, i, f32);
        for (int cd = 0; cd < CD; cd++)
            a = fmaf(ldin(obv, cd, f32), ldin(lW, cd * COUT + i, f32), a);
        b2[i] = a;
    }
}

// ---------------------------------------------------------------------------
// repack decoder gate weights into MFMA A-fragment order:
// WtA[((tap*7 + k0)*12 + mt)*64 + lane]*8+j ; m=mt*32+(lane&31);
// gate=m/96 (f,i,g,o), d=m%96; ch = k0*16+(lane>>5)*8+j (0..111, >=104 pad)
// rec layout: ch 0..7 = x, 8..103 = h
// ---------------------------------------------------------------------------
__global__ void repack_mfma_k(const float* __restrict__ Kf, const float* __restrict__ Ki,
                              const float* __restrict__ Kc, const float* __restrict__ dWof,
                              short* __restrict__ WtA)
{
    int lin = blockIdx.x * 256 + threadIdx.x;
    if (lin >= 9 * 7 * 12 * 64) return;
    int lane = lin & 63;
    int rest = lin >> 6;
    int mt  = rest % 12;
    int k07 = rest / 12;
    int k0  = k07 % 7;
    int tap = k07 / 7;
    int m = mt * 32 + (lane & 31);
    int gate = m / 96, d = m % 96;
    int chb = k0 * 16 + (lane >> 5) * 8;
    #pragma unroll
    for (int j = 0; j < 8; j++) {
        int ch = chb + j;
        float v = 0.f;
        if (ch < 104) {
            if (gate == 0)      v = Kf[((size_t)d * CD + ch) * 9 + tap];
            else if (gate == 1) v = Ki[((size_t)d * CD + ch) * 9 + tap];
            else if (gate == 2) v = Kc[((size_t)d * CD + ch) * 9 + tap];
            else                v = (tap == 4) ? dWof[ch * HD + d] : 0.f;
        }
        WtA[(size_t)lin * 8 + j] = f2bs(v);
    }
}

// ---------------------------------------------------------------------------
// repack encoder weights: EW[((k0*12 + mt)*64 + lane)*8+j]
// rec layout: ch 0..15 = x, 16..111 = h (matches eW rows directly)
// ---------------------------------------------------------------------------
__global__ void repack_enc_k(const float* __restrict__ Wf, const float* __restrict__ Wi,
                             const float* __restrict__ Wc, const float* __restrict__ Wo,
                             short* __restrict__ EW)
{
    int lin = blockIdx.x * 256 + threadIdx.x;
    if (lin >= 7 * 12 * 64) return;
    int lane = lin & 63;
    int rest = lin >> 6;
    int mt = rest % 12;
    int k0 = rest / 12;
    int m = mt * 32 + (lane & 31);
    int gate = m / 96, d = m % 96;
    int chb = k0 * 16 + (lane >> 5) * 8;
    const float* W = (gate == 0) ? Wf : (gate == 1) ? Wi : (gate == 2) ? Wc : Wo;
    #pragma unroll
    for (int j = 0; j < 8; j++)
        EW[(size_t)lin * 8 + j] = f2bs(W[(chb + j) * HD + d]);
}

// ---------------------------------------------------------------------------
// repack combined out-head conv K2 into one MFMA m-tile (rows 0..7 = out ch):
// K2A[((tap*7 + k0)*64 + lane)*8+j]; k = k0*16+(lane>>5)*8+j -> h ch c = k-8
// ---------------------------------------------------------------------------
__global__ void repack_k2a_k(const float* __restrict__ K2, short* __restrict__ K2A)
{
    int lin = blockIdx.x * 256 + threadIdx.x;
    if (lin >= 9 * 7 * 64) return;
    int lane = lin & 63;
    int rest = lin >> 6;
    int k0 = rest % 7;
    int tap = rest / 7;
    int m = lane & 31;
    int kb = k0 * 16 + (lane >> 5) * 8;
    #pragma unroll
    for (int j = 0; j < 8; j++) {
        int c = kb + j - 8;
        float v = (m < 8 && c >= 0 && c < 96) ? K2[(c * 9 + tap) * 8 + m] : 0.f;
        K2A[(size_t)lin * 8 + j] = f2bs(v);
    }
}

// ---------------------------------------------------------------------------
// persistent kernel: whole enc+dec recurrence. grid 256 = 32 bands x 8 batch,
// block 256 = 4 waves, 1 block/CU. c in registers (48 f32/thread). enc h in
// LDS (zero grid syncs). dec: own 2 rows persist in LDS; halo rows via
// ping-pong global (agent-coherent 8B atomics) + manual grid barrier.
// out head fused as extra m-tile.
// ---------------------------------------------------------------------------
__global__ void __launch_bounds__(256, 1) net_k(
    const void* __restrict__ xe, const void* __restrict__ xd,
    short* __restrict__ hPA, short* __restrict__ hPB,
    void* __restrict__ out,
    const short* __restrict__ EW, const short* __restrict__ WtA,
    const short* __restrict__ K2A,
    const float* __restrict__ ebf, const float* __restrict__ ebi,
    const float* __restrict__ ebc, const float* __restrict__ ebo,
    const float* __restrict__ dbf, const float* __restrict__ dbi,
    const float* __restrict__ dbc, const float* __restrict__ dbo,
    const float* __restrict__ b2, const int* __restrict__ flag,
    int* __restrict__ bar)
{
    __shared__ short lds[4 * 66 * 120];       // 63,360 B
    const int f32 = *flag;
    const int tid  = threadIdx.x;
    const int b    = blockIdx.x & 7;
    const int band = blockIdx.x >> 3;         // 0..31
    const int y0   = band * 2;
    const int pix0 = y0 * 64;
    const int wave = tid >> 6, lane = tid & 63;
    const int n = lane & 31, kj = lane >> 5;
    const int px = wave * 32 + n;             // block-local pixel 0..127
    const int pg = pix0 + px;                 // global pixel
    const int4 z4 = make_int4(0, 0, 0, 0);
    int phase = 0;

    float cre[48];
    #pragma unroll
    for (int i = 0; i < 48; i++) cre[i] = 0.f;

    // ================= encoder phase: h entirely in LDS recs [px][120] =====
    #pragma unroll 1
    for (int t = 0; t < T_; t++) {
        // x staging: 16 ch x 32 quads
        #pragma unroll
        for (int it = 0; it < 2; it++) {
            int i = tid + it * 256;
            int ch = i & 15, q = i >> 4;
            size_t base = ((size_t)(b * T_ + t) * CIN + ch) * HW + pix0 + q * 4;
            short v0, v1, v2, v3;
            if (f32) {
                float4 f = *(const float4*)((const float*)xe + base);
                v0 = f2bs(f.x); v1 = f2bs(f.y); v2 = f2bs(f.z); v3 = f2bs(f.w);
            } else {
                short4 sv = *(const short4*)((const short*)xe + base);
                v0 = sv.x; v1 = sv.y; v2 = sv.z; v3 = sv.w;
            }
            int sb = q * 4;
            lds[(sb + 0) * 120 + ch] = v0;
            lds[(sb + 1) * 120 + ch] = v1;
            lds[(sb + 2) * 120 + ch] = v2;
            lds[(sb + 3) * 120 + ch] = v3;
        }
        __syncthreads();

        f32x16 acc[12];
        #pragma unroll
        for (int m = 0; m < 12; m++)
            #pragma unroll
            for (int r = 0; r < 16; r++) acc[m][r] = 0.f;

        const short* rec = &lds[px * 120];
        const int k0max = (t == 0) ? 1 : 7;
        #pragma unroll 1
        for (int k0 = 0; k0 < k0max; k0++) {
            bf16x8 bf = *(const bf16x8*)(rec + k0 * 16 + kj * 8);
            const short* a0 = EW + ((size_t)(k0 * 12) * 64 + lane) * 8;
            #pragma unroll
            for (int mt = 0; mt < 12; mt++)
                acc[mt] = __builtin_amdgcn_mfma_f32_32x32x16_bf16(
                    *(const bf16x8*)(a0 + (size_t)mt * 512), bf, acc[mt], 0, 0, 0);
        }
        __syncthreads();

        // epilogue: LSTM pointwise, c in regs, h -> own LDS rec (+16 offset)
        #pragma unroll
        for (int dt = 0; dt < 3; dt++) {
            #pragma unroll
            for (int r = 0; r < 16; r++) {
                int row = (r & 3) + 8 * (r >> 2) + 4 * kj;
                int d = dt * 32 + row;
                float fg = sigmf_(acc[dt][r]     + ebf[d]);
                float ig = sigmf_(acc[3 + dt][r] + ebi[d]);
                float gg = tanhf_(acc[6 + dt][r] + ebc[d]);
                float og = sigmf_(acc[9 + dt][r] + ebo[d]);
                int ci = dt * 16 + r;
                float cn = fmaf(cre[ci], fg, ig * gg);
                cre[ci] = cn;
                lds[px * 120 + 16 + d] = f2bs(tanhf_(cn) * og);
            }
        }
        __syncthreads();
        if (t == T_ - 1) {
            // publish final enc h to hPA (pixel-major 96-ch records), coherent
            int px2 = tid >> 1, half = tid & 1;
            short* gdst = hPA + ((size_t)b * HW + pix0 + px2) * 96 + half * 48;
            const short* lsrc = &lds[px2 * 120 + 16 + half * 48];
            #pragma unroll
            for (int s2 = 0; s2 < 6; s2++)
                st_coh16(gdst + s2 * 8, *(const int4*)(lsrc + s2 * 8));
        }
    }
    phase++; gridbar(bar, phase * 256);

    // ================= decoder phase =====
    #pragma unroll 1
    for (int tt = 0; tt <= T_; tt++) {
        short* hR  = (tt & 1) ? hPB : hPA;    // h_{tt-1}
        short* hWr = (tt & 1) ? hPA : hPB;    // h_tt

        if (tt == 0) {
            // zero pass: edge slots + ch pads
            #pragma unroll 1
            for (int i = tid; i < 648; i += 256) {
                int addr_sh;
                if (i < 120) {
                    int r = i / 30, rem = i % 30;
                    int s = (rem / 15) * 65;
                    addr_sh = (r * 66 + s) * 120 + (rem % 15) * 8;
                } else {
                    int z = i - 120;
                    addr_sh = (z >> 1) * 120 + 104 + (z & 1) * 8;
                }
                *(int4*)(&lds[addr_sh]) = z4;
            }
            __syncthreads();
            // full h staging: 4 rows x 64 recs x 12 chunks (coherent loads)
            int4 tmp[12]; int ss2[12], jj2[12];
            #pragma unroll
            for (int i = 0; i < 12; i++) {
                int c2 = tid + i * 256;
                int s = c2 / 12, j = c2 - s * 12;
                ss2[i] = s; jj2[i] = j;
                int y = y0 - 1 + (s >> 6);
                if ((unsigned)y < 64u)
                    tmp[i] = ld_coh16(hR + ((size_t)b * HW + (size_t)y * 64 + (s & 63)) * 96 + j * 8);
                else tmp[i] = z4;
            }
            #pragma unroll
            for (int i = 0; i < 12; i++) {
                int s = ss2[i];
                *(int4*)(&lds[((s >> 6) * 66 + 1 + (s & 63)) * 120 + 8 + jj2[i] * 8]) = tmp[i];
            }
        } else {
            // halo staging only: rows y0-1 (slot-row 0) and y0+2 (slot-row 3)
            int4 tmp[6]; int ss2[6], jj2[6];
            #pragma unroll
            for (int i = 0; i < 6; i++) {
                int c2 = tid + i * 256;           // 0..1535
                int s = c2 / 12, j = c2 - s * 12; // s 0..127
                int hi = s >> 6;                  // 0 top, 1 bottom
                int y = hi ? (y0 + 2) : (y0 - 1);
                ss2[i] = hi * 3 * 66 + 1 + (s & 63);
                jj2[i] = j;
                if ((unsigned)y < 64u)
                    tmp[i] = ld_coh16(hR + ((size_t)b * HW + (size_t)y * 64 + (s & 63)) * 96 + j * 8);
                else tmp[i] = z4;
            }
            #pragma unroll
            for (int i = 0; i < 6; i++)
                *(int4*)(&lds[ss2[i] * 120 + 8 + jj2[i] * 8]) = tmp[i];
        }
        // x staging: 4 rows x 8 ch x 16 quads (skip on final out-only pass)
        if (tt < T_) {
            #pragma unroll
            for (int it = 0; it < 2; it++) {
                int i = tid + it * 256;
                int ch = i & 7, q = (i >> 3) & 15, r = i >> 7;
                int y = y0 - 1 + r;
                short v0 = 0, v1 = 0, v2 = 0, v3 = 0;
                if ((unsigned)y < 64u) {
                    size_t base = ((size_t)(b * T_ + tt) * COUT + ch) * HW + y * 64 + q * 4;
                    if (f32) {
                        float4 f = *(const float4*)((const float*)xd + base);
                        v0 = f2bs(f.x); v1 = f2bs(f.y); v2 = f2bs(f.z); v3 = f2bs(f.w);
                    } else {
                        short4 sv = *(const short4*)((const short*)xd + base);
                        v0 = sv.x; v1 = sv.y; v2 = sv.z; v3 = sv.w;
                    }
                }
                int sb = r * 66 + 1 + q * 4;
                lds[(sb + 0) * 120 + ch] = v0;
                lds[(sb + 1) * 120 + ch] = v1;
                lds[(sb + 2) * 120 + ch] = v2;
                lds[(sb + 3) * 120 + ch] = v3;
            }
        }
        __syncthreads();

        const int rw = 1 + (wave >> 1);
        const int x0 = (wave & 1) * 32;

        f32x16 aF[9], aO[3], aOut;
        #pragma unroll
        for (int m = 0; m < 9; m++)
            #pragma unroll
            for (int r = 0; r < 16; r++) aF[m][r] = 0.f;
        #pragma unroll
        for (int m = 0; m < 3; m++)
            #pragma unroll
            for (int r = 0; r < 16; r++) aO[m][r] = 0.f;
        #pragma unroll
        for (int r = 0; r < 16; r++) aOut[r] = 0.f;

        // main tap loop: gates f,i,g (9 m-tiles) + fused out head (1 m-tile)
        #pragma unroll 1
        for (int tap = 0; tap < 9; tap++) {
            int dy = tap / 3 - 1, dx = tap - (tap / 3) * 3 - 1;
            const short* rec = &lds[((rw + dy) * 66 + 1 + x0 + n + dx) * 120];
            const short* ab = WtA + ((size_t)(tap * 7) * 12 * 64 + lane) * 8;
            const short* kb = K2A + ((size_t)(tap * 7) * 64 + lane) * 8;
            #pragma unroll 1
            for (int k0 = 0; k0 < 7; k0++) {
                bf16x8 bf = *(const bf16x8*)(rec + k0 * 16 + kj * 8);
                if (tt < T_) {
                    const short* a0 = ab + (size_t)k0 * 12 * 64 * 8;
                    #pragma unroll
                    for (int mt = 0; mt < 9; mt++)
                        aF[mt] = __builtin_amdgcn_mfma_f32_32x32x16_bf16(
                            *(const bf16x8*)(a0 + (size_t)mt * 512), bf, aF[mt], 0, 0, 0);
                }
                if (tt > 0)
                    aOut = __builtin_amdgcn_mfma_f32_32x32x16_bf16(
                        *(const bf16x8*)(kb + (size_t)k0 * 512), bf, aOut, 0, 0, 0);
            }
        }
        // o gate: center tap only, m-tiles 9..11
        if (tt < T_) {
            const short* rec = &lds[(rw * 66 + 1 + x0 + n) * 120];
            const short* ab = WtA + ((size_t)(4 * 7) * 12 * 64 + lane) * 8;
            #pragma unroll 1
            for (int k0 = 0; k0 < 7; k0++) {
                bf16x8 bf = *(const bf16x8*)(rec + k0 * 16 + kj * 8);
                const short* a0 = ab + (size_t)k0 * 12 * 64 * 8 + 9 * 512;
                #pragma unroll
                for (int mt = 0; mt < 3; mt++)
                    aO[mt] = __builtin_amdgcn_mfma_f32_32x32x16_bf16(
                        *(const bf16x8*)(a0 + (size_t)mt * 512), bf, aO[mt], 0, 0, 0);
            }
        }
        __syncthreads();

        // fused out store for step tt-1 (C rows 0..7 = out channels)
        if (tt > 0) {
            #pragma unroll
            for (int r = 0; r < 4; r++) {
                int o = r + 4 * kj;
                float v = aOut[r] + b2[o];
                size_t oadr = ((size_t)(b * T_ + (tt - 1)) * COUT + o) * HW + pg;
                if (f32) ((float*)out)[oadr] = v;
                else     ((bf16*)out)[oadr] = __float2bfloat16(v);
            }
        }

        if (tt < T_) {
            // epilogue: LSTM pointwise, c in regs, h -> own staged recs
            #pragma unroll
            for (int dt = 0; dt < 3; dt++) {
                #pragma unroll
                for (int r = 0; r < 16; r++) {
                    int row = (r & 3) + 8 * (r >> 2) + 4 * kj;
                    int d = dt * 32 + row;
                    float fg = sigmf_(aF[dt][r]     + dbf[d]);
                    float ig = sigmf_(aF[3 + dt][r] + dbi[d]);
                    float gg = tanhf_(aF[6 + dt][r] + dbc[d]);
                    float og = sigmf_(aO[dt][r]     + dbo[d]);
                    int ci = dt * 16 + r;
                    float cn = fmaf(cre[ci], fg, ig * gg);
                    cre[ci] = cn;
                    float hv = tanhf_(cn) * og;
                    lds[((1 + (px >> 6)) * 66 + 1 + (px & 63)) * 120 + 8 + d] = f2bs(hv);
                }
            }
            __syncthreads();
            // publish own 2 rows to hWr (pixel-major records), coherent
            int px2 = tid >> 1, half = tid & 1;
            short* gdst = hWr + ((size_t)b * HW + pix0 + px2) * 96 + half * 48;
            const short* lsrc = &lds[((1 + (px2 >> 6)) * 66 + 1 + (px2 & 63)) * 120 + 8 + half * 48];
            #pragma unroll
            for (int s2 = 0; s2 < 6; s2++)
                st_coh16(gdst + s2 * 8, *(const int4*)(lsrc + s2 * 8));
            phase++; gridbar(bar, phase * 256);
        }
        // no barrier after the final out-only pass (tt == T_)
    }
}

// ---------------------------------------------------------------------------
extern "C" void kernel_launch(void* const* d_in, const int* in_sizes, int n_in,
                              void* d_out, int out_size, void* d_ws, size_t ws_size,
                              hipStream_t stream)
{
    const void* enc_in = d_in[0];
    const void* dec_in = d_in[1];
    const void* eWf = d_in[2];  const void* ebf_ = d_in[3];
    const void* eWi = d_in[4];  const void* ebi_ = d_in[5];
    const void* eWc = d_in[6];  const void* ebc_ = d_in[7];
    const void* eWo = d_in[8];  const void* ebo_ = d_in[9];
    const void* dKf = d_in[10]; const void* dbf_ = d_in[11];
    const void* dKi = d_in[12]; const void* dbi_ = d_in[13];
    const void* dKc = d_in[14]; const void* dbc_ = d_in[15];
    const void* dWo = d_in[16]; const void* dbo_ = d_in[17];
    const void* oK  = d_in[18]; const void* obv = d_in[19];
    const void* lW  = d_in[20]; const void* lb  = d_in[21];

    int* flag = (int*)d_ws;
    int* bar  = (int*)d_ws + 8;
    float* ws = (float*)d_ws + 16;

    const int S = B_ * HD * HW;              // 3,145,728 state elems
    short* hPA = (short*)ws;                 // S shorts (pixel-major h)
    short* hPB = (short*)(ws + S / 2);       // S shorts
    float* Wbase = ws + S;
    float* Wf   = Wbase;
    float* Wi   = Wf + 10752;
    float* Wc   = Wi + 10752;
    float* Wo   = Wc + 10752;
    float* bfv  = Wo + 10752;
    float* biv  = bfv + 96;
    float* bcv  = biv + 96;
    float* bov  = bcv + 96;
    float* Kf   = bov + 96;
    float* Ki   = Kf + 89856;
    float* Kc   = Ki + 89856;
    float* dbfv = Kc + 89856;
    float* dbiv = dbfv + 96;
    float* dbcv = dbiv + 96;
    float* dWof = dbcv + 96;
    float* dbov = dWof + 9984;
    float* K2   = dbov + 96;
    float* b2   = K2 + 6912;
    short* WtA  = (short*)(b2 + 16);                  // 387,072 shorts
    short* EW   = (short*)(b2 + 16 + 193536);         // 43,008 shorts
    short* K2A  = (short*)(b2 + 16 + 193536 + 21504); // 32,256 shorts

    detect_k<<<dim3(1), dim3(64), 0, stream>>>(eWf, flag, bar);
    prep_k<<<dim3(1263), dim3(256), 0, stream>>>(
        eWf, eWi, eWc, eWo, ebf_, ebi_, ebc_, ebo_,
        dKf, dKi, dKc, dbf_, dbi_, dbc_, dWo, dbo_, Wbase, flag);
    combine_k<<<dim3(4), dim3(256), 0, stream>>>(oK, obv, lW, lb, K2, b2, flag);
    repack_mfma_k<<<dim3(189), dim3(256), 0, stream>>>(Kf, Ki, Kc, dWof, WtA);
    repack_enc_k<<<dim3(21), dim3(256), 0, stream>>>(Wf, Wi, Wc, Wo, EW);
    repack_k2a_k<<<dim3(16), dim3(256), 0, stream>>>(K2, K2A);

    net_k<<<dim3(256), dim3(256), 0, stream>>>(
        enc_in, dec_in, hPA, hPB, d_out,
        EW, WtA, K2A,
        bfv, biv, bcv, bov,
        dbfv, dbiv, dbcv, dbov,
        b2, flag, bar);
}

// Round 2
// 1413.284 us; speedup vs baseline: 1.3260x; 1.1929x over previous
//
#include <hip/hip_runtime.h>
#include <hip/hip_bf16.h>

#define B_   8
#define T_   12
#define CIN  16
#define HD   96
#define COUT 8
#define CE   112
#define CD   104
#define HW   4096
#define WIMG 64

typedef __hip_bfloat16 bf16;
typedef __attribute__((ext_vector_type(8))) short bf16x8;   // 8 bf16 (4 VGPRs)
typedef __attribute__((ext_vector_type(16))) float f32x16;  // MFMA 32x32 C/D

__device__ __forceinline__ float b2f(bf16 v) { return __bfloat162float(v); }
__device__ __forceinline__ float sigmf_(float x) { return 1.0f / (1.0f + __expf(-x)); }
__device__ __forceinline__ float tanhf_(float x) { return 2.0f / (1.0f + __expf(-2.0f * x)) - 1.0f; }

__device__ __forceinline__ float ldin(const void* p, long i, int f32) {
    return f32 ? ((const float*)p)[i] : b2f(((const bf16*)p)[i]);
}
__device__ __forceinline__ short f2bs(float v) {
    __hip_bfloat16 hv = __float2bfloat16(v);
    return *reinterpret_cast<short*>(&hv);
}

// ---------------------------------------------------------------------------
// device-coherent 16B access as 2x 8B agent-scope atomics (bypass L1/L2 ->
// served at the coherence point). All cross-block payload uses these, so no
// cache-invalidating fences are needed anywhere; weights stay L2-resident.
// ---------------------------------------------------------------------------
__device__ __forceinline__ int4 ld_coh16(const short* p) {
    const unsigned long long* q = (const unsigned long long*)p;
    unsigned long long a = __hip_atomic_load(q,     __ATOMIC_RELAXED, __HIP_MEMORY_SCOPE_AGENT);
    unsigned long long c = __hip_atomic_load(q + 1, __ATOMIC_RELAXED, __HIP_MEMORY_SCOPE_AGENT);
    int4 r;
    ((unsigned long long*)&r)[0] = a;
    ((unsigned long long*)&r)[1] = c;
    return r;
}
__device__ __forceinline__ void st_coh16(short* p, int4 v) {
    unsigned long long* q = (unsigned long long*)p;
    __hip_atomic_store(q,     ((unsigned long long*)&v)[0], __ATOMIC_RELAXED, __HIP_MEMORY_SCOPE_AGENT);
    __hip_atomic_store(q + 1, ((unsigned long long*)&v)[1], __ATOMIC_RELAXED, __HIP_MEMORY_SCOPE_AGENT);
}

// ---------------------------------------------------------------------------
// neighbor-pair progress sync. prog[bid*16] is a per-block monotonic step
// counter on its own 64B line (no hot-line contention). Publisher: coherent
// h stores -> vmcnt drain -> block barrier -> thread0 bypass-stores counter.
// Consumer: poll only its 2 vertical neighbors' counters.
// Safe by capacity: grid=256 blocks, 1 block/CU -> all resident.
// ---------------------------------------------------------------------------
__device__ __forceinline__ void wait_prog(const int* p, int need) {
    while (__hip_atomic_load(p, __ATOMIC_RELAXED, __HIP_MEMORY_SCOPE_AGENT) < need)
        __builtin_amdgcn_s_sleep(1);
}

// ---------------------------------------------------------------------------
// detect: fp32 vs bf16 input dtype; also zero the per-block progress flags
// ---------------------------------------------------------------------------
__global__ void detect_k(const void* w, int* flag, int* prog) {
    int t = threadIdx.x;
    __hip_atomic_store(&prog[t * 16], 0, __ATOMIC_RELAXED, __HIP_MEMORY_SCOPE_AGENT);
    if (t == 0) {
        const unsigned short* u = (const unsigned short*)w;
        int bad = 0;
        for (int i = 0; i < 64; i++) {
            unsigned short v = u[i];
            unsigned e = (v >> 7) & 0xFF;
            if (!(v == 0 || (e >= 90 && e <= 128))) bad++;
        }
        *flag = (bad > 8) ? 1 : 0;
    }
}

// ---------------------------------------------------------------------------
// prep: convert all recurrent-loop weights (bf16 or fp32) -> fp32 workspace
// ---------------------------------------------------------------------------
__global__ void prep_k(
    const void* p0, const void* p1, const void* p2, const void* p3,
    const void* p4, const void* p5, const void* p6, const void* p7,
    const void* p8, const void* p9, const void* p10, const void* p11,
    const void* p12, const void* p13, const void* p14, const void* p15,
    float* __restrict__ dst, const int* __restrict__ flag)
{
    const int f32 = *flag;
    const void* srcs[16] = {p0,p1,p2,p3,p4,p5,p6,p7,p8,p9,p10,p11,p12,p13,p14,p15};
    const int sizes[16] = {10752,10752,10752,10752, 96,96,96,96,
                           89856,89856,89856, 96,96,96, 9984, 96};
    int i = blockIdx.x * blockDim.x + threadIdx.x;
    float* d = dst;
    #pragma unroll 1
    for (int s = 0; s < 16; s++) {
        if (i < sizes[s]) { d[i] = ldin(srcs[s], i, f32); return; }
        i -= sizes[s];
        d += sizes[s];
    }
}

// ---------------------------------------------------------------------------
// combine: fold output head conv(oK)+ob then linear(lW)+lb into one conv
// ---------------------------------------------------------------------------
__global__ void combine_k(const void* __restrict__ oK, const void* __restrict__ obv,
                          const void* __restrict__ lW, const void* __restrict__ lb,
                          float* __restrict__ K2, float* __restrict__ b2,
                          const int* __restrict__ flag)
{
    const int f32 = *flag;
    int i = blockIdx.x * blockDim.x + threadIdx.x;
    if (i < HD * 9) {
        float acc[8] = {0,0,0,0,0,0,0,0};
        for (int cd = 0; cd < CD; cd++) {
            float kv = ldin(oK, cd * (HD * 9) + i, f32);
            #pragma unroll
            for (int o = 0; o < 8; o++)
                acc[o] = fmaf(kv, ldin(lW, cd * COUT + o, f32), acc[o]);
        }
        #pragma unroll
        for (int o = 0; o < 8; o++) K2[i * 8 + o] = acc[o];
    }
    if (i < COUT) {
        float a = ldin(lb, i, f32);
        for (int cd = 0; cd < CD; cd++)
            a = fmaf(ldin(obv, cd, f32), ldin(lW, cd * COUT + i, f32), a);
        b2[i] = a;
    }
}

// ---------------------------------------------------------------------------
// repack decoder gate weights into MFMA A-fragment order:
// WtA[((tap*7 + k0)*12 + mt)*64 + lane]*8+j ; m=mt*32+(lane&31);
// gate=m/96 (f,i,g,o), d=m%96; ch = k0*16+(lane>>5)*8+j (0..111, >=104 pad)
// rec layout: ch 0..7 = x, 8..103 = h
// ---------------------------------------------------------------------------
__global__ void repack_mfma_k(const float* __restrict__ Kf, const float* __restrict__ Ki,
                              const float* __restrict__ Kc, const float* __restrict__ dWof,
                              short* __restrict__ WtA)
{
    int lin = blockIdx.x * 256 + threadIdx.x;
    if (lin >= 9 * 7 * 12 * 64) return;
    int lane = lin & 63;
    int rest = lin >> 6;
    int mt  = rest % 12;
    int k07 = rest / 12;
    int k0  = k07 % 7;
    int tap = k07 / 7;
    int m = mt * 32 + (lane & 31);
    int gate = m / 96, d = m % 96;
    int chb = k0 * 16 + (lane >> 5) * 8;
    #pragma unroll
    for (int j = 0; j < 8; j++) {
        int ch = chb + j;
        float v = 0.f;
        if (ch < 104) {
            if (gate == 0)      v = Kf[((size_t)d * CD + ch) * 9 + tap];
            else if (gate == 1) v = Ki[((size_t)d * CD + ch) * 9 + tap];
            else if (gate == 2) v = Kc[((size_t)d * CD + ch) * 9 + tap];
            else                v = (tap == 4) ? dWof[ch * HD + d] : 0.f;
        }
        WtA[(size_t)lin * 8 + j] = f2bs(v);
    }
}

// ---------------------------------------------------------------------------
// repack encoder weights: EW[((k0*12 + mt)*64 + lane)*8+j]
// rec layout: ch 0..15 = x, 16..111 = h (matches eW rows directly)
// ---------------------------------------------------------------------------
__global__ void repack_enc_k(const float* __restrict__ Wf, const float* __restrict__ Wi,
                             const float* __restrict__ Wc, const float* __restrict__ Wo,
                             short* __restrict__ EW)
{
    int lin = blockIdx.x * 256 + threadIdx.x;
    if (lin >= 7 * 12 * 64) return;
    int lane = lin & 63;
    int rest = lin >> 6;
    int mt = rest % 12;
    int k0 = rest / 12;
    int m = mt * 32 + (lane & 31);
    int gate = m / 96, d = m % 96;
    int chb = k0 * 16 + (lane >> 5) * 8;
    const float* W = (gate == 0) ? Wf : (gate == 1) ? Wi : (gate == 2) ? Wc : Wo;
    #pragma unroll
    for (int j = 0; j < 8; j++)
        EW[(size_t)lin * 8 + j] = f2bs(W[(chb + j) * HD + d]);
}

// ---------------------------------------------------------------------------
// repack combined out-head conv K2 into one MFMA m-tile (rows 0..7 = out ch):
// K2A[((tap*7 + k0)*64 + lane)*8+j]; k = k0*16+(lane>>5)*8+j -> h ch c = k-8
// ---------------------------------------------------------------------------
__global__ void repack_k2a_k(const float* __restrict__ K2, short* __restrict__ K2A)
{
    int lin = blockIdx.x * 256 + threadIdx.x;
    if (lin >= 9 * 7 * 64) return;
    int lane = lin & 63;
    int rest = lin >> 6;
    int k0 = rest % 7;
    int tap = rest / 7;
    int m = lane & 31;
    int kb = k0 * 16 + (lane >> 5) * 8;
    #pragma unroll
    for (int j = 0; j < 8; j++) {
        int c = kb + j - 8;
        float v = (m < 8 && c >= 0 && c < 96) ? K2[(c * 9 + tap) * 8 + m] : 0.f;
        K2A[(size_t)lin * 8 + j] = f2bs(v);
    }
}

// ---------------------------------------------------------------------------
// persistent kernel: whole enc+dec recurrence. grid 256 = 32 bands x 8 batch,
// block 256 = 4 waves, 1 block/CU. c in registers (48 f32/thread). enc h in
// LDS (zero syncs). dec: own 2 rows persist in LDS; halo rows via ping-pong
// global (agent-coherent) + NEIGHBOR-ONLY progress flags (no grid barrier).
// out head fused as extra m-tile.
// ---------------------------------------------------------------------------
__global__ void __launch_bounds__(256, 1) net_k(
    const void* __restrict__ xe, const void* __restrict__ xd,
    short* __restrict__ hPA, short* __restrict__ hPB,
    void* __restrict__ out,
    const short* __restrict__ EW, const short* __restrict__ WtA,
    const short* __restrict__ K2A,
    const float* __restrict__ ebf, const float* __restrict__ ebi,
    const float* __restrict__ ebc, const float* __restrict__ ebo,
    const float* __restrict__ dbf, const float* __restrict__ dbi,
    const float* __restrict__ dbc, const float* __restrict__ dbo,
    const float* __restrict__ b2, const int* __restrict__ flag,
    int* __restrict__ prog)
{
    __shared__ short lds[4 * 66 * 120];       // 63,360 B
    const int f32 = *flag;
    const int tid  = threadIdx.x;
    const int b    = blockIdx.x & 7;
    const int band = blockIdx.x >> 3;         // 0..31
    const int y0   = band * 2;
    const int pix0 = y0 * 64;
    const int wave = tid >> 6, lane = tid & 63;
    const int n = lane & 31, kj = lane >> 5;
    const int px = wave * 32 + n;             // block-local pixel 0..127
    const int pg = pix0 + px;                 // global pixel
    const int4 z4 = make_int4(0, 0, 0, 0);

    float cre[48];
    #pragma unroll
    for (int i = 0; i < 48; i++) cre[i] = 0.f;

    // ================= encoder phase: h entirely in LDS recs [px][120] =====
    #pragma unroll 1
    for (int t = 0; t < T_; t++) {
        // x staging: 16 ch x 32 quads
        #pragma unroll
        for (int it = 0; it < 2; it++) {
            int i = tid + it * 256;
            int ch = i & 15, q = i >> 4;
            size_t base = ((size_t)(b * T_ + t) * CIN + ch) * HW + pix0 + q * 4;
            short v0, v1, v2, v3;
            if (f32) {
                float4 f = *(const float4*)((const float*)xe + base);
                v0 = f2bs(f.x); v1 = f2bs(f.y); v2 = f2bs(f.z); v3 = f2bs(f.w);
            } else {
                short4 sv = *(const short4*)((const short*)xe + base);
                v0 = sv.x; v1 = sv.y; v2 = sv.z; v3 = sv.w;
            }
            int sb = q * 4;
            lds[(sb + 0) * 120 + ch] = v0;
            lds[(sb + 1) * 120 + ch] = v1;
            lds[(sb + 2) * 120 + ch] = v2;
            lds[(sb + 3) * 120 + ch] = v3;
        }
        __syncthreads();

        f32x16 acc[12];
        #pragma unroll
        for (int m = 0; m < 12; m++)
            #pragma unroll
            for (int r = 0; r < 16; r++) acc[m][r] = 0.f;

        const short* rec = &lds[px * 120];
        const int k0max = (t == 0) ? 1 : 7;
        #pragma unroll 1
        for (int k0 = 0; k0 < k0max; k0++) {
            bf16x8 bf = *(const bf16x8*)(rec + k0 * 16 + kj * 8);
            const short* a0 = EW + ((size_t)(k0 * 12) * 64 + lane) * 8;
            #pragma unroll
            for (int mt = 0; mt < 12; mt++)
                acc[mt] = __builtin_amdgcn_mfma_f32_32x32x16_bf16(
                    *(const bf16x8*)(a0 + (size_t)mt * 512), bf, acc[mt], 0, 0, 0);
        }
        __syncthreads();

        // epilogue: LSTM pointwise, c in regs, h -> own LDS rec (+16 offset)
        #pragma unroll
        for (int dt = 0; dt < 3; dt++) {
            #pragma unroll
            for (int r = 0; r < 16; r++) {
                int row = (r & 3) + 8 * (r >> 2) + 4 * kj;
                int d = dt * 32 + row;
                float fg = sigmf_(acc[dt][r]     + ebf[d]);
                float ig = sigmf_(acc[3 + dt][r] + ebi[d]);
                float gg = tanhf_(acc[6 + dt][r] + ebc[d]);
                float og = sigmf_(acc[9 + dt][r] + ebo[d]);
                int ci = dt * 16 + r;
                float cn = fmaf(cre[ci], fg, ig * gg);
                cre[ci] = cn;
                lds[px * 120 + 16 + d] = f2bs(tanhf_(cn) * og);
            }
        }
        __syncthreads();
        if (t == T_ - 1) {
            // publish final enc h to hPA (pixel-major 96-ch records), coherent
            int px2 = tid >> 1, half = tid & 1;
            short* gdst = hPA + ((size_t)b * HW + pix0 + px2) * 96 + half * 48;
            const short* lsrc = &lds[px2 * 120 + 16 + half * 48];
            #pragma unroll
            for (int s2 = 0; s2 < 6; s2++)
                st_coh16(gdst + s2 * 8, *(const int4*)(lsrc + s2 * 8));
        }
    }
    // signal: enc h published (prog = 1)
    asm volatile("s_waitcnt vmcnt(0)" ::: "memory");
    __syncthreads();
    if (tid == 0)
        __hip_atomic_store(&prog[blockIdx.x * 16], 1, __ATOMIC_RELAXED, __HIP_MEMORY_SCOPE_AGENT);

    // ================= decoder phase =====
    #pragma unroll 1
    for (int tt = 0; tt <= T_; tt++) {
        short* hR  = (tt & 1) ? hPB : hPA;    // h_{tt-1}
        short* hWr = (tt & 1) ? hPA : hPB;    // h_tt

        // neighbor sync: need h_{tt-1} of bands band+-1 published (prog>=tt+1)
        if (tid < 2) {
            int nb = band + (tid ? 1 : -1);
            if ((unsigned)nb < 32u)
                wait_prog(prog + (((nb << 3) | b) << 4), tt + 1);
        }
        __syncthreads();

        if (tt == 0) {
            // zero pass: edge slots + ch pads
            #pragma unroll 1
            for (int i = tid; i < 648; i += 256) {
                int addr_sh;
                if (i < 120) {
                    int r = i / 30, rem = i % 30;
                    int s = (rem / 15) * 65;
                    addr_sh = (r * 66 + s) * 120 + (rem % 15) * 8;
                } else {
                    int z = i - 120;
                    addr_sh = (z >> 1) * 120 + 104 + (z & 1) * 8;
                }
                *(int4*)(&lds[addr_sh]) = z4;
            }
            __syncthreads();
            // full h staging: 4 rows x 64 recs x 12 chunks (coherent loads)
            int4 tmp[12]; int ss2[12], jj2[12];
            #pragma unroll
            for (int i = 0; i < 12; i++) {
                int c2 = tid + i * 256;
                int s = c2 / 12, j = c2 - s * 12;
                ss2[i] = s; jj2[i] = j;
                int y = y0 - 1 + (s >> 6);
                if ((unsigned)y < 64u)
                    tmp[i] = ld_coh16(hR + ((size_t)b * HW + (size_t)y * 64 + (s & 63)) * 96 + j * 8);
                else tmp[i] = z4;
            }
            #pragma unroll
            for (int i = 0; i < 12; i++) {
                int s = ss2[i];
                *(int4*)(&lds[((s >> 6) * 66 + 1 + (s & 63)) * 120 + 8 + jj2[i] * 8]) = tmp[i];
            }
        } else {
            // halo staging only: rows y0-1 (slot-row 0) and y0+2 (slot-row 3)
            int4 tmp[6]; int ss2[6], jj2[6];
            #pragma unroll
            for (int i = 0; i < 6; i++) {
                int c2 = tid + i * 256;           // 0..1535
                int s = c2 / 12, j = c2 - s * 12; // s 0..127
                int hi = s >> 6;                  // 0 top, 1 bottom
                int y = hi ? (y0 + 2) : (y0 - 1);
                ss2[i] = hi * 3 * 66 + 1 + (s & 63);
                jj2[i] = j;
                if ((unsigned)y < 64u)
                    tmp[i] = ld_coh16(hR + ((size_t)b * HW + (size_t)y * 64 + (s & 63)) * 96 + j * 8);
                else tmp[i] = z4;
            }
            #pragma unroll
            for (int i = 0; i < 6; i++)
                *(int4*)(&lds[ss2[i] * 120 + 8 + jj2[i] * 8]) = tmp[i];
        }
        // x staging: 4 rows x 8 ch x 16 quads (skip on final out-only pass)
        if (tt < T_) {
            #pragma unroll
            for (int it = 0; it < 2; it++) {
                int i = tid + it * 256;
                int ch = i & 7, q = (i >> 3) & 15, r = i >> 7;
                int y = y0 - 1 + r;
                short v0 = 0, v1 = 0, v2 = 0, v3 = 0;
                if ((unsigned)y < 64u) {
                    size_t base = ((size_t)(b * T_ + tt) * COUT + ch) * HW + y * 64 + q * 4;
                    if (f32) {
                        float4 f = *(const float4*)((const float*)xd + base);
                        v0 = f2bs(f.x); v1 = f2bs(f.y); v2 = f2bs(f.z); v3 = f2bs(f.w);
                    } else {
                        short4 sv = *(const short4*)((const short*)xd + base);
                        v0 = sv.x; v1 = sv.y; v2 = sv.z; v3 = sv.w;
                    }
                }
                int sb = r * 66 + 1 + q * 4;
                lds[(sb + 0) * 120 + ch] = v0;
                lds[(sb + 1) * 120 + ch] = v1;
                lds[(sb + 2) * 120 + ch] = v2;
                lds[(sb + 3) * 120 + ch] = v3;
            }
        }
        __syncthreads();

        const int rw = 1 + (wave >> 1);
        const int x0 = (wave & 1) * 32;

        f32x16 aF[9], aO[3], aOut;
        #pragma unroll
        for (int m = 0; m < 9; m++)
            #pragma unroll
            for (int r = 0; r < 16; r++) aF[m][r] = 0.f;
        #pragma unroll
        for (int m = 0; m < 3; m++)
            #pragma unroll
            for (int r = 0; r < 16; r++) aO[m][r] = 0.f;
        #pragma unroll
        for (int r = 0; r < 16; r++) aOut[r] = 0.f;

        // main tap loop: gates f,i,g (9 m-tiles) + fused out head (1 m-tile)
        #pragma unroll 1
        for (int tap = 0; tap < 9; tap++) {
            int dy = tap / 3 - 1, dx = tap - (tap / 3) * 3 - 1;
            const short* rec = &lds[((rw + dy) * 66 + 1 + x0 + n + dx) * 120];
            const short* ab = WtA + ((size_t)(tap * 7) * 12 * 64 + lane) * 8;
            const short* kb = K2A + ((size_t)(tap * 7) * 64 + lane) * 8;
            #pragma unroll 1
            for (int k0 = 0; k0 < 7; k0++) {
                bf16x8 bf = *(const bf16x8*)(rec + k0 * 16 + kj * 8);
                if (tt < T_) {
                    const short* a0 = ab + (size_t)k0 * 12 * 64 * 8;
                    #pragma unroll
                    for (int mt = 0; mt < 9; mt++)
                        aF[mt] = __builtin_amdgcn_mfma_f32_32x32x16_bf16(
                            *(const bf16x8*)(a0 + (size_t)mt * 512), bf, aF[mt], 0, 0, 0);
                }
                if (tt > 0)
                    aOut = __builtin_amdgcn_mfma_f32_32x32x16_bf16(
                        *(const bf16x8*)(kb + (size_t)k0 * 512), bf, aOut, 0, 0, 0);
            }
        }
        // o gate: center tap only, m-tiles 9..11
        if (tt < T_) {
            const short* rec = &lds[(rw * 66 + 1 + x0 + n) * 120];
            const short* ab = WtA + ((size_t)(4 * 7) * 12 * 64 + lane) * 8;
            #pragma unroll 1
            for (int k0 = 0; k0 < 7; k0++) {
                bf16x8 bf = *(const bf16x8*)(rec + k0 * 16 + kj * 8);
                const short* a0 = ab + (size_t)k0 * 12 * 64 * 8 + 9 * 512;
                #pragma unroll
                for (int mt = 0; mt < 3; mt++)
                    aO[mt] = __builtin_amdgcn_mfma_f32_32x32x16_bf16(
                        *(const bf16x8*)(a0 + (size_t)mt * 512), bf, aO[mt], 0, 0, 0);
            }
        }
        __syncthreads();

        // fused out store for step tt-1 (C rows 0..7 = out channels)
        if (tt > 0) {
            #pragma unroll
            for (int r = 0; r < 4; r++) {
                int o = r + 4 * kj;
                float v = aOut[r] + b2[o];
                size_t oadr = ((size_t)(b * T_ + (tt - 1)) * COUT + o) * HW + pg;
                if (f32) ((float*)out)[oadr] = v;
                else     ((bf16*)out)[oadr] = __float2bfloat16(v);
            }
        }

        if (tt < T_) {
            // epilogue: LSTM pointwise, c in regs, h -> own staged recs
            #pragma unroll
            for (int dt = 0; dt < 3; dt++) {
                #pragma unroll
                for (int r = 0; r < 16; r++) {
                    int row = (r & 3) + 8 * (r >> 2) + 4 * kj;
                    int d = dt * 32 + row;
                    float fg = sigmf_(aF[dt][r]     + dbf[d]);
                    float ig = sigmf_(aF[3 + dt][r] + dbi[d]);
                    float gg = tanhf_(aF[6 + dt][r] + dbc[d]);
                    float og = sigmf_(aO[dt][r]     + dbo[d]);
                    int ci = dt * 16 + r;
                    float cn = fmaf(cre[ci], fg, ig * gg);
                    cre[ci] = cn;
                    float hv = tanhf_(cn) * og;
                    lds[((1 + (px >> 6)) * 66 + 1 + (px & 63)) * 120 + 8 + d] = f2bs(hv);
                }
            }
            __syncthreads();
            // publish own 2 rows to hWr (pixel-major records), coherent
            int px2 = tid >> 1, half = tid & 1;
            short* gdst = hWr + ((size_t)b * HW + pix0 + px2) * 96 + half * 48;
            const short* lsrc = &lds[((1 + (px2 >> 6)) * 66 + 1 + (px2 & 63)) * 120 + 8 + half * 48];
            #pragma unroll
            for (int s2 = 0; s2 < 6; s2++)
                st_coh16(gdst + s2 * 8, *(const int4*)(lsrc + s2 * 8));
            // signal: h_tt published (prog = tt+2)
            asm volatile("s_waitcnt vmcnt(0)" ::: "memory");
            __syncthreads();
            if (tid == 0)
                __hip_atomic_store(&prog[blockIdx.x * 16], tt + 2,
                                   __ATOMIC_RELAXED, __HIP_MEMORY_SCOPE_AGENT);
        }
        // no signal after the final out-only pass (tt == T_)
    }
}

// ---------------------------------------------------------------------------
extern "C" void kernel_launch(void* const* d_in, const int* in_sizes, int n_in,
                              void* d_out, int out_size, void* d_ws, size_t ws_size,
                              hipStream_t stream)
{
    const void* enc_in = d_in[0];
    const void* dec_in = d_in[1];
    const void* eWf = d_in[2];  const void* ebf_ = d_in[3];
    const void* eWi = d_in[4];  const void* ebi_ = d_in[5];
    const void* eWc = d_in[6];  const void* ebc_ = d_in[7];
    const void* eWo = d_in[8];  const void* ebo_ = d_in[9];
    const void* dKf = d_in[10]; const void* dbf_ = d_in[11];
    const void* dKi = d_in[12]; const void* dbi_ = d_in[13];
    const void* dKc = d_in[14]; const void* dbc_ = d_in[15];
    const void* dWo = d_in[16]; const void* dbo_ = d_in[17];
    const void* oK  = d_in[18]; const void* obv = d_in[19];
    const void* lW  = d_in[20]; const void* lb  = d_in[21];

    int* flag = (int*)d_ws;
    int* prog = (int*)d_ws + 16;             // 256 slots x 16 ints (64B stride)
    float* ws = (float*)d_ws + 16 + 4096;

    const int S = B_ * HD * HW;              // 3,145,728 state elems
    short* hPA = (short*)ws;                 // S shorts (pixel-major h)
    short* hPB = (short*)(ws + S / 2);       // S shorts
    float* Wbase = ws + S;
    float* Wf   = Wbase;
    float* Wi   = Wf + 10752;
    float* Wc   = Wi + 10752;
    float* Wo   = Wc + 10752;
    float* bfv  = Wo + 10752;
    float* biv  = bfv + 96;
    float* bcv  = biv + 96;
    float* bov  = bcv + 96;
    float* Kf   = bov + 96;
    float* Ki   = Kf + 89856;
    float* Kc   = Ki + 89856;
    float* dbfv = Kc + 89856;
    float* dbiv = dbfv + 96;
    float* dbcv = dbiv + 96;
    float* dWof = dbcv + 96;
    float* dbov = dWof + 9984;
    float* K2   = dbov + 96;
    float* b2   = K2 + 6912;
    short* WtA  = (short*)(b2 + 16);                  // 387,072 shorts
    short* EW   = (short*)(b2 + 16 + 193536);         // 43,008 shorts
    short* K2A  = (short*)(b2 + 16 + 193536 + 21504); // 32,256 shorts

    detect_k<<<dim3(1), dim3(256), 0, stream>>>(eWf, flag, prog);
    prep_k<<<dim3(1263), dim3(256), 0, stream>>>(
        eWf, eWi, eWc, eWo, ebf_, ebi_, ebc_, ebo_,
        dKf, dKi, dKc, dbf_, dbi_, dbc_, dWo, dbo_, Wbase, flag);
    combine_k<<<dim3(4), dim3(256), 0, stream>>>(oK, obv, lW, lb, K2, b2, flag);
    repack_mfma_k<<<dim3(189), dim3(256), 0, stream>>>(Kf, Ki, Kc, dWof, WtA);
    repack_enc_k<<<dim3(21), dim3(256), 0, stream>>>(Wf, Wi, Wc, Wo, EW);
    repack_k2a_k<<<dim3(16), dim3(256), 0, stream>>>(K2, K2A);

    net_k<<<dim3(256), dim3(256), 0, stream>>>(
        enc_in, dec_in, hPA, hPB, d_out,
        EW, WtA, K2A,
        bfv, biv, bcv, bov,
        dbfv, dbiv, dbcv, dbov,
        b2, flag, prog);
}

// Round 4
// 1344.173 us; speedup vs baseline: 1.3941x; 1.0514x over previous
//
#include <hip/hip_runtime.h>
#include <hip/hip_bf16.h>

#define B_   8
#define T_   12
#define CIN  16
#define HD   96
#define COUT 8
#define CE   112
#define CD   104
#define HW   4096
#define WIMG 64

typedef __hip_bfloat16 bf16;
typedef __attribute__((ext_vector_type(8))) short bf16x8;   // 8 bf16 (4 VGPRs)
typedef __attribute__((ext_vector_type(16))) float f32x16;  // MFMA 32x32 C/D
typedef __attribute__((ext_vector_type(4))) int i32x4;      // 16B asm payload

__device__ __forceinline__ float b2f(bf16 v) { return __bfloat162float(v); }
__device__ __forceinline__ float sigmf_(float x) { return 1.0f / (1.0f + __expf(-x)); }
__device__ __forceinline__ float tanhf_(float x) { return 2.0f / (1.0f + __expf(-2.0f * x)) - 1.0f; }

__device__ __forceinline__ float ldin(const void* p, long i, int f32) {
    return f32 ? ((const float*)p)[i] : b2f(((const bf16*)p)[i]);
}
__device__ __forceinline__ short f2bs(float v) {
    __hip_bfloat16 hv = __float2bfloat16(v);
    return *reinterpret_cast<short*>(&hv);
}

// ---------------------------------------------------------------------------
// 16B device-coherent (bypass L1+L2 -> coherence point) plain loads/stores.
// Non-atomic, fully coalescable; vmcnt-tracked. Batch: N loads -> vm0() ->
// consume. ext_vector types map cleanly to VGPR quads for the "v" constraint.
// ---------------------------------------------------------------------------
__device__ __forceinline__ i32x4 ldB16(const short* p) {
    i32x4 r;
    asm volatile("global_load_dwordx4 %0, %1, off sc0 sc1"
                 : "=v"(r) : "v"(p) : "memory");
    return r;
}
__device__ __forceinline__ void stB16(short* p, i32x4 v) {
    asm volatile("global_store_dwordx4 %0, %1, off sc0 sc1"
                 :: "v"(p), "v"(v) : "memory");
}
__device__ __forceinline__ void vm0() {
    asm volatile("s_waitcnt vmcnt(0)" ::: "memory");
}

// ---------------------------------------------------------------------------
// neighbor-pair progress sync. prog[bid*16]: per-block monotonic step counter
// on its own 64B line. Publisher: coherent stores -> vmcnt drain -> block
// barrier -> thread0 stores counter. Consumer polls only 2 vertical neighbors.
// Safe by capacity: grid=256 blocks, 1 block/CU -> all resident.
// ---------------------------------------------------------------------------
__device__ __forceinline__ void wait_prog(const int* p, int need) {
    while (__hip_atomic_load(p, __ATOMIC_RELAXED, __HIP_MEMORY_SCOPE_AGENT) < need)
        __builtin_amdgcn_s_sleep(1);
}

__device__ __forceinline__ int detect_flag(const void* w) {
    const unsigned short* u = (const unsigned short*)w;
    int bad = 0;
    for (int i = 0; i < 64; i++) {
        unsigned short v = u[i];
        unsigned e = (v >> 7) & 0xFF;
        if (!(v == 0 || (e >= 90 && e <= 128))) bad++;
    }
    return (bad > 8) ? 1 : 0;
}

// ---------------------------------------------------------------------------
// ONE fused setup kernel (replaces detect/prep/combine/repack x3).
// All repacks read RAW inputs (bf16 or fp32 via ldin); combine folded into
// the K2A repack. Block ranges:
//   0-2   : bias conversion (8 arrays x 96 -> fp32)
//   3     : b2 (out-head bias fold, 8) + global flag write
//   4     : zero per-block progress flags
//   5-25  : EW   (encoder weights, 5376 frags)
//   26-214: WtA  (decoder gate weights, 48384 frags)
//   215-230: K2A (combined out-head conv, 4032 frags, combine inline)
// ---------------------------------------------------------------------------
__global__ void setup_k(
    const void* eWf, const void* ebf_, const void* eWi, const void* ebi_,
    const void* eWc, const void* ebc_, const void* eWo, const void* ebo_,
    const void* dKf, const void* dbf_, const void* dKi, const void* dbi_,
    const void* dKc, const void* dbc_, const void* dWo, const void* dbo_,
    const void* oK,  const void* obv,  const void* lW,  const void* lb,
    float* __restrict__ biases, float* __restrict__ b2,
    short* __restrict__ EW, short* __restrict__ WtA, short* __restrict__ K2A,
    int* __restrict__ flag, int* __restrict__ prog)
{
    const int f = detect_flag(eWf);
    const int bid = blockIdx.x, tid = threadIdx.x;

    if (bid < 3) {                               // biases
        int idx = bid * 256 + tid;
        if (idx < 768) {
            const void* srcs[8] = {ebf_, ebi_, ebc_, ebo_, dbf_, dbi_, dbc_, dbo_};
            biases[idx] = ldin(srcs[idx / 96], idx % 96, f);
        }
        return;
    }
    if (bid == 3) {                              // b2 + flag
        if (tid < COUT) {
            float a = ldin(lb, tid, f);
            for (int cd = 0; cd < CD; cd++)
                a = fmaf(ldin(obv, cd, f), ldin(lW, cd * COUT + tid, f), a);
            b2[tid] = a;
        }
        if (tid == 32) *flag = f;
        return;
    }
    if (bid == 4) {                              // zero progress flags
        __hip_atomic_store(&prog[tid * 16], 0, __ATOMIC_RELAXED, __HIP_MEMORY_SCOPE_AGENT);
        return;
    }
    if (bid < 26) {                              // EW
        int lin = (bid - 5) * 256 + tid;
        if (lin >= 7 * 12 * 64) return;
        int lane = lin & 63;
        int rest = lin >> 6;
        int mt = rest % 12;
        int k0 = rest / 12;
        int m = mt * 32 + (lane & 31);
        int gate = m / 96, d = m % 96;
        int chb = k0 * 16 + (lane >> 5) * 8;
        const void* W = (gate == 0) ? eWf : (gate == 1) ? eWi : (gate == 2) ? eWc : eWo;
        #pragma unroll
        for (int j = 0; j < 8; j++)
            EW[(size_t)lin * 8 + j] = f2bs(ldin(W, (size_t)(chb + j) * HD + d, f));
        return;
    }
    if (bid < 215) {                             // WtA
        int lin = (bid - 26) * 256 + tid;
        if (lin >= 9 * 7 * 12 * 64) return;
        int lane = lin & 63;
        int rest = lin >> 6;
        int mt  = rest % 12;
        int k07 = rest / 12;
        int k0  = k07 % 7;
        int tap = k07 / 7;
        int m = mt * 32 + (lane & 31);
        int gate = m / 96, d = m % 96;
        int chb = k0 * 16 + (lane >> 5) * 8;
        #pragma unroll
        for (int j = 0; j < 8; j++) {
            int ch = chb + j;
            float v = 0.f;
            if (ch < 104) {
                long ki = ((long)d * CD + ch) * 9 + tap;
                if (gate == 0)      v = ldin(dKf, ki, f);
                else if (gate == 1) v = ldin(dKi, ki, f);
                else if (gate == 2) v = ldin(dKc, ki, f);
                else                v = (tap == 4) ? ldin(dWo, (long)ch * HD + d, f) : 0.f;
            }
            WtA[(size_t)lin * 8 + j] = f2bs(v);
        }
        return;
    }
    {                                            // K2A with combine inline
        int lin = (bid - 215) * 256 + tid;
        if (lin >= 9 * 7 * 64) return;
        int lane = lin & 63;
        int rest = lin >> 6;
        int k0 = rest % 7;
        int tap = rest / 7;
        int m = lane & 31;
        int kb = k0 * 16 + (lane >> 5) * 8;
        #pragma unroll 1
        for (int j = 0; j < 8; j++) {
            int c = kb + j - 8;
            float v = 0.f;
            if (m < 8 && c >= 0 && c < 96) {
                // K2[(c*9+tap)*8+m] = sum_cd oK[cd][c*9+tap] * lW[cd][m]
                long i = (long)c * 9 + tap;
                for (int cd = 0; cd < CD; cd++)
                    v = fmaf(ldin(oK, (long)cd * (HD * 9) + i, f),
                             ldin(lW, (long)cd * COUT + m, f), v);
            }
            K2A[(size_t)lin * 8 + j] = f2bs(v);
        }
    }
}

// ---------------------------------------------------------------------------
// persistent kernel: whole enc+dec recurrence. grid 256 = 32 bands x 8 batch,
// block 256 = 4 waves, 1 block/CU. c in registers (48 f32/thread). enc h in
// LDS (zero syncs). dec: own 2 rows persist in LDS; halo rows via ping-pong
// global (16B coherent-bypass) + NEIGHBOR-ONLY progress flags.
// out head fused as extra m-tile.
// ---------------------------------------------------------------------------
__global__ void __launch_bounds__(256, 1) net_k(
    const void* __restrict__ xe, const void* __restrict__ xd,
    short* __restrict__ hPA, short* __restrict__ hPB,
    void* __restrict__ out,
    const short* __restrict__ EW, const short* __restrict__ WtA,
    const short* __restrict__ K2A,
    const float* __restrict__ ebf, const float* __restrict__ ebi,
    const float* __restrict__ ebc, const float* __restrict__ ebo,
    const float* __restrict__ dbf, const float* __restrict__ dbi,
    const float* __restrict__ dbc, const float* __restrict__ dbo,
    const float* __restrict__ b2, const int* __restrict__ flag,
    int* __restrict__ prog)
{
    __shared__ short lds[4 * 66 * 120];       // 63,360 B
    const int f32 = *flag;
    const int tid  = threadIdx.x;
    const int b    = blockIdx.x & 7;
    const int band = blockIdx.x >> 3;         // 0..31
    const int y0   = band * 2;
    const int pix0 = y0 * 64;
    const int wave = tid >> 6, lane = tid & 63;
    const int n = lane & 31, kj = lane >> 5;
    const int px = wave * 32 + n;             // block-local pixel 0..127
    const int pg = pix0 + px;                 // global pixel
    const i32x4 z4 = {0, 0, 0, 0};

    float cre[48];
    #pragma unroll
    for (int i = 0; i < 48; i++) cre[i] = 0.f;

    // ================= encoder phase: h entirely in LDS recs [px][120] =====
    #pragma unroll 1
    for (int t = 0; t < T_; t++) {
        // x staging: 16 ch x 32 quads
        #pragma unroll
        for (int it = 0; it < 2; it++) {
            int i = tid + it * 256;
            int ch = i & 15, q = i >> 4;
            size_t base = ((size_t)(b * T_ + t) * CIN + ch) * HW + pix0 + q * 4;
            short v0, v1, v2, v3;
            if (f32) {
                float4 f = *(const float4*)((const float*)xe + base);
                v0 = f2bs(f.x); v1 = f2bs(f.y); v2 = f2bs(f.z); v3 = f2bs(f.w);
            } else {
                short4 sv = *(const short4*)((const short*)xe + base);
                v0 = sv.x; v1 = sv.y; v2 = sv.z; v3 = sv.w;
            }
            int sb = q * 4;
            lds[(sb + 0) * 120 + ch] = v0;
            lds[(sb + 1) * 120 + ch] = v1;
            lds[(sb + 2) * 120 + ch] = v2;
            lds[(sb + 3) * 120 + ch] = v3;
        }
        __syncthreads();

        f32x16 acc[12];
        #pragma unroll
        for (int m = 0; m < 12; m++)
            #pragma unroll
            for (int r = 0; r < 16; r++) acc[m][r] = 0.f;

        const short* rec = &lds[px * 120];
        const int k0max = (t == 0) ? 1 : 7;
        #pragma unroll 2
        for (int k0 = 0; k0 < k0max; k0++) {
            bf16x8 bf = *(const bf16x8*)(rec + k0 * 16 + kj * 8);
            const short* a0 = EW + ((size_t)(k0 * 12) * 64 + lane) * 8;
            #pragma unroll
            for (int mt = 0; mt < 12; mt++)
                acc[mt] = __builtin_amdgcn_mfma_f32_32x32x16_bf16(
                    *(const bf16x8*)(a0 + (size_t)mt * 512), bf, acc[mt], 0, 0, 0);
        }
        __syncthreads();

        // epilogue: LSTM pointwise, c in regs, h -> own LDS rec (+16 offset)
        #pragma unroll
        for (int dt = 0; dt < 3; dt++) {
            #pragma unroll
            for (int r = 0; r < 16; r++) {
                int row = (r & 3) + 8 * (r >> 2) + 4 * kj;
                int d = dt * 32 + row;
                float fg = sigmf_(acc[dt][r]     + ebf[d]);
                float ig = sigmf_(acc[3 + dt][r] + ebi[d]);
                float gg = tanhf_(acc[6 + dt][r] + ebc[d]);
                float og = sigmf_(acc[9 + dt][r] + ebo[d]);
                int ci = dt * 16 + r;
                float cn = fmaf(cre[ci], fg, ig * gg);
                cre[ci] = cn;
                lds[px * 120 + 16 + d] = f2bs(tanhf_(cn) * og);
            }
        }
        __syncthreads();
        if (t == T_ - 1) {
            // publish final enc h to hPA (pixel-major 96-ch records), coherent
            int px2 = tid >> 1, half = tid & 1;
            short* gdst = hPA + ((size_t)b * HW + pix0 + px2) * 96 + half * 48;
            const short* lsrc = &lds[px2 * 120 + 16 + half * 48];
            #pragma unroll
            for (int s2 = 0; s2 < 6; s2++)
                stB16(gdst + s2 * 8, *(const i32x4*)(lsrc + s2 * 8));
        }
    }
    // signal: enc h published (prog = 1)
    vm0();
    __syncthreads();
    if (tid == 0)
        __hip_atomic_store(&prog[blockIdx.x * 16], 1, __ATOMIC_RELAXED, __HIP_MEMORY_SCOPE_AGENT);

    // ================= decoder phase =====
    #pragma unroll 1
    for (int tt = 0; tt <= T_; tt++) {
        short* hR  = (tt & 1) ? hPB : hPA;    // h_{tt-1}
        short* hWr = (tt & 1) ? hPA : hPB;    // h_tt

        if (tt == 0) {
            // zero pass: edge slots + ch pads (disjoint from all staging)
            #pragma unroll 1
            for (int i = tid; i < 648; i += 256) {
                int addr_sh;
                if (i < 120) {
                    int r = i / 30, rem = i % 30;
                    int s = (rem / 15) * 65;
                    addr_sh = (r * 66 + s) * 120 + (rem % 15) * 8;
                } else {
                    int z = i - 120;
                    addr_sh = (z >> 1) * 120 + 104 + (z & 1) * 8;
                }
                *(i32x4*)(&lds[addr_sh]) = z4;
            }
        }
        // x staging FIRST (no neighbor dependency -> overlaps the wait):
        // 4 rows x 8 ch x 16 quads (skip on final out-only pass)
        if (tt < T_) {
            #pragma unroll
            for (int it = 0; it < 2; it++) {
                int i = tid + it * 256;
                int ch = i & 7, q = (i >> 3) & 15, r = i >> 7;
                int y = y0 - 1 + r;
                short v0 = 0, v1 = 0, v2 = 0, v3 = 0;
                if ((unsigned)y < 64u) {
                    size_t base = ((size_t)(b * T_ + tt) * COUT + ch) * HW + y * 64 + q * 4;
                    if (f32) {
                        float4 f = *(const float4*)((const float*)xd + base);
                        v0 = f2bs(f.x); v1 = f2bs(f.y); v2 = f2bs(f.z); v3 = f2bs(f.w);
                    } else {
                        short4 sv = *(const short4*)((const short*)xd + base);
                        v0 = sv.x; v1 = sv.y; v2 = sv.z; v3 = sv.w;
                    }
                }
                int sb = r * 66 + 1 + q * 4;
                lds[(sb + 0) * 120 + ch] = v0;
                lds[(sb + 1) * 120 + ch] = v1;
                lds[(sb + 2) * 120 + ch] = v2;
                lds[(sb + 3) * 120 + ch] = v3;
            }
        }

        // neighbor sync: need h_{tt-1} of bands band+-1 published (prog>=tt+1)
        if (tid < 2) {
            int nb = band + (tid ? 1 : -1);
            if ((unsigned)nb < 32u)
                wait_prog(prog + (((nb << 3) | b) << 4), tt + 1);
        }
        __syncthreads();

        if (tt == 0) {
            // full h staging: 4 rows x 64 recs x 12 chunks (coherent loads)
            i32x4 tmp[12]; int ss2[12], jj2[12];
            #pragma unroll
            for (int i = 0; i < 12; i++) {
                int c2 = tid + i * 256;
                int s = c2 / 12, j = c2 - s * 12;
                ss2[i] = s; jj2[i] = j;
                int y = y0 - 1 + (s >> 6);
                if ((unsigned)y < 64u)
                    tmp[i] = ldB16(hR + ((size_t)b * HW + (size_t)y * 64 + (s & 63)) * 96 + j * 8);
                else tmp[i] = z4;
            }
            vm0();
            #pragma unroll
            for (int i = 0; i < 12; i++) {
                int s = ss2[i];
                *(i32x4*)(&lds[((s >> 6) * 66 + 1 + (s & 63)) * 120 + 8 + jj2[i] * 8]) = tmp[i];
            }
        } else {
            // halo staging only: rows y0-1 (slot-row 0) and y0+2 (slot-row 3)
            i32x4 tmp[6]; int ss2[6], jj2[6];
            #pragma unroll
            for (int i = 0; i < 6; i++) {
                int c2 = tid + i * 256;           // 0..1535
                int s = c2 / 12, j = c2 - s * 12; // s 0..127
                int hi = s >> 6;                  // 0 top, 1 bottom
                int y = hi ? (y0 + 2) : (y0 - 1);
                ss2[i] = hi * 3 * 66 + 1 + (s & 63);
                jj2[i] = j;
                if ((unsigned)y < 64u)
                    tmp[i] = ldB16(hR + ((size_t)b * HW + (size_t)y * 64 + (s & 63)) * 96 + j * 8);
                else tmp[i] = z4;
            }
            vm0();
            #pragma unroll
            for (int i = 0; i < 6; i++)
                *(i32x4*)(&lds[ss2[i] * 120 + 8 + jj2[i] * 8]) = tmp[i];
        }
        __syncthreads();

        const int rw = 1 + (wave >> 1);
        const int x0 = (wave & 1) * 32;

        f32x16 aF[9], aO[3], aOut;
        #pragma unroll
        for (int m = 0; m < 9; m++)
            #pragma unroll
            for (int r = 0; r < 16; r++) aF[m][r] = 0.f;
        #pragma unroll
        for (int m = 0; m < 3; m++)
            #pragma unroll
            for (int r = 0; r < 16; r++) aO[m][r] = 0.f;
        #pragma unroll
        for (int r = 0; r < 16; r++) aOut[r] = 0.f;

        // main tap loop: gates f,i,g (9 m-tiles) + fused out head (1 m-tile)
        #pragma unroll 1
        for (int tap = 0; tap < 9; tap++) {
            int dy = tap / 3 - 1, dx = tap - (tap / 3) * 3 - 1;
            const short* rec = &lds[((rw + dy) * 66 + 1 + x0 + n + dx) * 120];
            const short* ab = WtA + ((size_t)(tap * 7) * 12 * 64 + lane) * 8;
            const short* kb = K2A + ((size_t)(tap * 7) * 64 + lane) * 8;
            #pragma unroll 2
            for (int k0 = 0; k0 < 7; k0++) {
                bf16x8 bf = *(const bf16x8*)(rec + k0 * 16 + kj * 8);
                if (tt < T_) {
                    const short* a0 = ab + (size_t)k0 * 12 * 64 * 8;
                    #pragma unroll
                    for (int mt = 0; mt < 9; mt++)
                        aF[mt] = __builtin_amdgcn_mfma_f32_32x32x16_bf16(
                            *(const bf16x8*)(a0 + (size_t)mt * 512), bf, aF[mt], 0, 0, 0);
                }
                if (tt > 0)
                    aOut = __builtin_amdgcn_mfma_f32_32x32x16_bf16(
                        *(const bf16x8*)(kb + (size_t)k0 * 512), bf, aOut, 0, 0, 0);
            }
        }
        // o gate: center tap only, m-tiles 9..11
        if (tt < T_) {
            const short* rec = &lds[(rw * 66 + 1 + x0 + n) * 120];
            const short* ab = WtA + ((size_t)(4 * 7) * 12 * 64 + lane) * 8;
            #pragma unroll 2
            for (int k0 = 0; k0 < 7; k0++) {
                bf16x8 bf = *(const bf16x8*)(rec + k0 * 16 + kj * 8);
                const short* a0 = ab + (size_t)k0 * 12 * 64 * 8 + 9 * 512;
                #pragma unroll
                for (int mt = 0; mt < 3; mt++)
                    aO[mt] = __builtin_amdgcn_mfma_f32_32x32x16_bf16(
                        *(const bf16x8*)(a0 + (size_t)mt * 512), bf, aO[mt], 0, 0, 0);
            }
        }
        __syncthreads();

        // fused out store for step tt-1 (C rows 0..7 = out channels)
        if (tt > 0) {
            #pragma unroll
            for (int r = 0; r < 4; r++) {
                int o = r + 4 * kj;
                float v = aOut[r] + b2[o];
                size_t oadr = ((size_t)(b * T_ + (tt - 1)) * COUT + o) * HW + pg;
                if (f32) ((float*)out)[oadr] = v;
                else     ((bf16*)out)[oadr] = __float2bfloat16(v);
            }
        }

        if (tt < T_) {
            // epilogue: LSTM pointwise, c in regs, h -> own staged recs
            #pragma unroll
            for (int dt = 0; dt < 3; dt++) {
                #pragma unroll
                for (int r = 0; r < 16; r++) {
                    int row = (r & 3) + 8 * (r >> 2) + 4 * kj;
                    int d = dt * 32 + row;
                    float fg = sigmf_(aF[dt][r]     + dbf[d]);
                    float ig = sigmf_(aF[3 + dt][r] + dbi[d]);
                    float gg = tanhf_(aF[6 + dt][r] + dbc[d]);
                    float og = sigmf_(aO[dt][r]     + dbo[d]);
                    int ci = dt * 16 + r;
                    float cn = fmaf(cre[ci], fg, ig * gg);
                    cre[ci] = cn;
                    float hv = tanhf_(cn) * og;
                    lds[((1 + (px >> 6)) * 66 + 1 + (px & 63)) * 120 + 8 + d] = f2bs(hv);
                }
            }
            __syncthreads();
            // publish own 2 rows to hWr (pixel-major records), coherent
            int px2 = tid >> 1, half = tid & 1;
            short* gdst = hWr + ((size_t)b * HW + pix0 + px2) * 96 + half * 48;
            const short* lsrc = &lds[((1 + (px2 >> 6)) * 66 + 1 + (px2 & 63)) * 120 + 8 + half * 48];
            #pragma unroll
            for (int s2 = 0; s2 < 6; s2++)
                stB16(gdst + s2 * 8, *(const i32x4*)(lsrc + s2 * 8));
            // signal: h_tt published (prog = tt+2)
            vm0();
            __syncthreads();
            if (tid == 0)
                __hip_atomic_store(&prog[blockIdx.x * 16], tt + 2,
                                   __ATOMIC_RELAXED, __HIP_MEMORY_SCOPE_AGENT);
        }
        // no signal after the final out-only pass (tt == T_)
    }
}

// ---------------------------------------------------------------------------
extern "C" void kernel_launch(void* const* d_in, const int* in_sizes, int n_in,
                              void* d_out, int out_size, void* d_ws, size_t ws_size,
                              hipStream_t stream)
{
    const void* enc_in = d_in[0];
    const void* dec_in = d_in[1];
    const void* eWf = d_in[2];  const void* ebf_ = d_in[3];
    const void* eWi = d_in[4];  const void* ebi_ = d_in[5];
    const void* eWc = d_in[6];  const void* ebc_ = d_in[7];
    const void* eWo = d_in[8];  const void* ebo_ = d_in[9];
    const void* dKf = d_in[10]; const void* dbf_ = d_in[11];
    const void* dKi = d_in[12]; const void* dbi_ = d_in[13];
    const void* dKc = d_in[14]; const void* dbc_ = d_in[15];
    const void* dWo = d_in[16]; const void* dbo_ = d_in[17];
    const void* oK  = d_in[18]; const void* obv = d_in[19];
    const void* lW  = d_in[20]; const void* lb  = d_in[21];

    int* flag = (int*)d_ws;
    int* prog = (int*)d_ws + 16;             // 256 slots x 16 ints (64B stride)
    float* ws = (float*)d_ws + 16 + 4096;

    const int S = B_ * HD * HW;              // 3,145,728 state elems
    short* hPA = (short*)ws;                 // S shorts (pixel-major h)
    short* hPB = (short*)(ws + S / 2);       // S shorts
    float* biases = ws + S;                  // 8 x 96 fp32
    float* b2   = biases + 768;              // 16
    short* WtA  = (short*)(b2 + 16);                  // 387,072 shorts
    short* EW   = (short*)(b2 + 16 + 193536);         // 43,008 shorts
    short* K2A  = (short*)(b2 + 16 + 193536 + 21504); // 32,256 shorts

    setup_k<<<dim3(231), dim3(256), 0, stream>>>(
        eWf, ebf_, eWi, ebi_, eWc, ebc_, eWo, ebo_,
        dKf, dbf_, dKi, dbi_, dKc, dbc_, dWo, dbo_,
        oK, obv, lW, lb,
        biases, b2, EW, WtA, K2A, flag, prog);

    net_k<<<dim3(256), dim3(256), 0, stream>>>(
        enc_in, dec_in, hPA, hPB, d_out,
        EW, WtA, K2A,
        biases + 0, biases + 96, biases + 192, biases + 288,
        biases + 384, biases + 480, biases + 576, biases + 672,
        b2, flag, prog);
}

// Round 5
// 1046.917 us; speedup vs baseline: 1.7900x; 1.2839x over previous
//
#include <hip/hip_runtime.h>
#include <hip/hip_bf16.h>

#define B_   8
#define T_   12
#define CIN  16
#define HD   96
#define COUT 8
#define CE   112
#define CD   104
#define HW   4096
#define WIMG 64

typedef __hip_bfloat16 bf16;
typedef __attribute__((ext_vector_type(8))) short bf16x8;   // 8 bf16 (4 VGPRs)
typedef __attribute__((ext_vector_type(16))) float f32x16;  // MFMA 32x32 C/D
typedef __attribute__((ext_vector_type(4))) int i32x4;      // 16B asm payload

__device__ __forceinline__ float b2f(bf16 v) { return __bfloat162float(v); }
__device__ __forceinline__ float sigmf_(float x) { return 1.0f / (1.0f + __expf(-x)); }
__device__ __forceinline__ float tanhf_(float x) { return 2.0f / (1.0f + __expf(-2.0f * x)) - 1.0f; }

__device__ __forceinline__ float ldin(const void* p, long i, int f32) {
    return f32 ? ((const float*)p)[i] : b2f(((const bf16*)p)[i]);
}
__device__ __forceinline__ short f2bs(float v) {
    __hip_bfloat16 hv = __float2bfloat16(v);
    return *reinterpret_cast<short*>(&hv);
}

// ---------------------------------------------------------------------------
// MFMA via inline asm with "+a": forces the accumulator into AGPRs.
// This frees ~200 VGPRs of accumulator state so the k0-loop A-fragment
// prefetch pipeline has registers to live in (the round-4 bottleneck:
// VGPR_Count==256 left zero headroom -> compiler serialized every load).
// ---------------------------------------------------------------------------
__device__ __forceinline__ void mfma_a(f32x16& acc, bf16x8 a, bf16x8 b) {
    asm("v_mfma_f32_32x32x16_bf16 %0, %1, %2, %0"
        : "+a"(acc) : "v"(a), "v"(b));
}

// ---------------------------------------------------------------------------
// 16B device-coherent (bypass L1+L2 -> coherence point) plain loads/stores.
// ---------------------------------------------------------------------------
__device__ __forceinline__ i32x4 ldB16(const short* p) {
    i32x4 r;
    asm volatile("global_load_dwordx4 %0, %1, off sc0 sc1"
                 : "=v"(r) : "v"(p) : "memory");
    return r;
}
__device__ __forceinline__ void stB16(short* p, i32x4 v) {
    asm volatile("global_store_dwordx4 %0, %1, off sc0 sc1"
                 :: "v"(p), "v"(v) : "memory");
}
__device__ __forceinline__ void vm0() {
    asm volatile("s_waitcnt vmcnt(0)" ::: "memory");
}

// ---------------------------------------------------------------------------
// neighbor-pair progress sync. prog[bid*16]: per-block monotonic step counter
// on its own 64B line. Publisher: coherent stores -> vmcnt drain -> block
// barrier -> thread0 stores counter. Consumer polls only 2 vertical neighbors.
// ---------------------------------------------------------------------------
__device__ __forceinline__ void wait_prog(const int* p, int need) {
    while (__hip_atomic_load(p, __ATOMIC_RELAXED, __HIP_MEMORY_SCOPE_AGENT) < need)
        __builtin_amdgcn_s_sleep(1);
}

__device__ __forceinline__ int detect_flag(const void* w) {
    const unsigned short* u = (const unsigned short*)w;
    int bad = 0;
    for (int i = 0; i < 64; i++) {
        unsigned short v = u[i];
        unsigned e = (v >> 7) & 0xFF;
        if (!(v == 0 || (e >= 90 && e <= 128))) bad++;
    }
    return (bad > 8) ? 1 : 0;
}

// ---------------------------------------------------------------------------
// ONE fused setup kernel. Block ranges:
//   0-2: biases  3: b2+flag  4: prog zero  5-25: EW  26-214: WtA  215-230: K2A
// ---------------------------------------------------------------------------
__global__ void setup_k(
    const void* eWf, const void* ebf_, const void* eWi, const void* ebi_,
    const void* eWc, const void* ebc_, const void* eWo, const void* ebo_,
    const void* dKf, const void* dbf_, const void* dKi, const void* dbi_,
    const void* dKc, const void* dbc_, const void* dWo, const void* dbo_,
    const void* oK,  const void* obv,  const void* lW,  const void* lb,
    float* __restrict__ biases, float* __restrict__ b2,
    short* __restrict__ EW, short* __restrict__ WtA, short* __restrict__ K2A,
    int* __restrict__ flag, int* __restrict__ prog)
{
    const int f = detect_flag(eWf);
    const int bid = blockIdx.x, tid = threadIdx.x;

    if (bid < 3) {                               // biases
        int idx = bid * 256 + tid;
        if (idx < 768) {
            const void* srcs[8] = {ebf_, ebi_, ebc_, ebo_, dbf_, dbi_, dbc_, dbo_};
            biases[idx] = ldin(srcs[idx / 96], idx % 96, f);
        }
        return;
    }
    if (bid == 3) {                              // b2 + flag
        if (tid < COUT) {
            float a = ldin(lb, tid, f);
            for (int cd = 0; cd < CD; cd++)
                a = fmaf(ldin(obv, cd, f), ldin(lW, cd * COUT + tid, f), a);
            b2[tid] = a;
        }
        if (tid == 32) *flag = f;
        return;
    }
    if (bid == 4) {                              // zero progress flags
        __hip_atomic_store(&prog[tid * 16], 0, __ATOMIC_RELAXED, __HIP_MEMORY_SCOPE_AGENT);
        return;
    }
    if (bid < 26) {                              // EW
        int lin = (bid - 5) * 256 + tid;
        if (lin >= 7 * 12 * 64) return;
        int lane = lin & 63;
        int rest = lin >> 6;
        int mt = rest % 12;
        int k0 = rest / 12;
        int m = mt * 32 + (lane & 31);
        int gate = m / 96, d = m % 96;
        int chb = k0 * 16 + (lane >> 5) * 8;
        const void* W = (gate == 0) ? eWf : (gate == 1) ? eWi : (gate == 2) ? eWc : eWo;
        #pragma unroll
        for (int j = 0; j < 8; j++)
            EW[(size_t)lin * 8 + j] = f2bs(ldin(W, (size_t)(chb + j) * HD + d, f));
        return;
    }
    if (bid < 215) {                             // WtA
        int lin = (bid - 26) * 256 + tid;
        if (lin >= 9 * 7 * 12 * 64) return;
        int lane = lin & 63;
        int rest = lin >> 6;
        int mt  = rest % 12;
        int k07 = rest / 12;
        int k0  = k07 % 7;
        int tap = k07 / 7;
        int m = mt * 32 + (lane & 31);
        int gate = m / 96, d = m % 96;
        int chb = k0 * 16 + (lane >> 5) * 8;
        #pragma unroll
        for (int j = 0; j < 8; j++) {
            int ch = chb + j;
            float v = 0.f;
            if (ch < 104) {
                long ki = ((long)d * CD + ch) * 9 + tap;
                if (gate == 0)      v = ldin(dKf, ki, f);
                else if (gate == 1) v = ldin(dKi, ki, f);
                else if (gate == 2) v = ldin(dKc, ki, f);
                else                v = (tap == 4) ? ldin(dWo, (long)ch * HD + d, f) : 0.f;
            }
            WtA[(size_t)lin * 8 + j] = f2bs(v);
        }
        return;
    }
    {                                            // K2A with combine inline
        int lin = (bid - 215) * 256 + tid;
        if (lin >= 9 * 7 * 64) return;
        int lane = lin & 63;
        int rest = lin >> 6;
        int k0 = rest % 7;
        int tap = rest / 7;
        int m = lane & 31;
        int kb = k0 * 16 + (lane >> 5) * 8;
        #pragma unroll 1
        for (int j = 0; j < 8; j++) {
            int c = kb + j - 8;
            float v = 0.f;
            if (m < 8 && c >= 0 && c < 96) {
                long i = (long)c * 9 + tap;
                for (int cd = 0; cd < CD; cd++)
                    v = fmaf(ldin(oK, (long)cd * (HD * 9) + i, f),
                             ldin(lW, (long)cd * COUT + m, f), v);
            }
            K2A[(size_t)lin * 8 + j] = f2bs(v);
        }
    }
}

// ---------------------------------------------------------------------------
// decoder fragment pack loader: 9 gate A-frags (optional) + 1 out-head frag
// + 1 B-frag (LDS rec). Used by the 1-deep software pipeline.
// ---------------------------------------------------------------------------
__device__ __forceinline__ void ldfragsD(bf16x8* A, bf16x8& K, bf16x8& B,
                                         const short* ab, const short* kb,
                                         const short* rec, int k0, int kj, int ldA)
{
    const short* a0 = ab + (size_t)k0 * 12 * 64 * 8;
    if (ldA) {
        #pragma unroll
        for (int mt = 0; mt < 9; mt++)
            A[mt] = *(const bf16x8*)(a0 + (size_t)mt * 512);
    }
    K = *(const bf16x8*)(kb + (size_t)k0 * 512);
    B = *(const bf16x8*)(rec + k0 * 16 + kj * 8);
}

// ---------------------------------------------------------------------------
// persistent kernel: whole enc+dec recurrence. grid 256 = 32 bands x 8 batch,
// block 256 = 4 waves, 1 block/CU. c in regs; acc in AGPRs (asm MFMA);
// A-fragments 1-deep prefetched (VGPRs freed by AGPR accs). Halo via
// ping-pong global (16B coherent-bypass) + neighbor-only progress flags.
// ---------------------------------------------------------------------------
__global__ void __launch_bounds__(256, 1) net_k(
    const void* __restrict__ xe, const void* __restrict__ xd,
    short* __restrict__ hPA, short* __restrict__ hPB,
    void* __restrict__ out,
    const short* __restrict__ EW, const short* __restrict__ WtA,
    const short* __restrict__ K2A,
    const float* __restrict__ ebf, const float* __restrict__ ebi,
    const float* __restrict__ ebc, const float* __restrict__ ebo,
    const float* __restrict__ dbf, const float* __restrict__ dbi,
    const float* __restrict__ dbc, const float* __restrict__ dbo,
    const float* __restrict__ b2, const int* __restrict__ flag,
    int* __restrict__ prog)
{
    __shared__ short lds[4 * 66 * 120];       // 63,360 B
    const int f32 = *flag;
    const int tid  = threadIdx.x;
    const int b    = blockIdx.x & 7;
    const int band = blockIdx.x >> 3;         // 0..31
    const int y0   = band * 2;
    const int pix0 = y0 * 64;
    const int wave = tid >> 6, lane = tid & 63;
    const int n = lane & 31, kj = lane >> 5;
    const int px = wave * 32 + n;             // block-local pixel 0..127
    const int pg = pix0 + px;                 // global pixel
    const i32x4 z4 = {0, 0, 0, 0};

    float cre[48];
    #pragma unroll
    for (int i = 0; i < 48; i++) cre[i] = 0.f;

    // ================= encoder phase: h entirely in LDS recs [px][120] =====
    #pragma unroll 1
    for (int t = 0; t < T_; t++) {
        // x staging: 16 ch x 32 quads
        #pragma unroll
        for (int it = 0; it < 2; it++) {
            int i = tid + it * 256;
            int ch = i & 15, q = i >> 4;
            size_t base = ((size_t)(b * T_ + t) * CIN + ch) * HW + pix0 + q * 4;
            short v0, v1, v2, v3;
            if (f32) {
                float4 f = *(const float4*)((const float*)xe + base);
                v0 = f2bs(f.x); v1 = f2bs(f.y); v2 = f2bs(f.z); v3 = f2bs(f.w);
            } else {
                short4 sv = *(const short4*)((const short*)xe + base);
                v0 = sv.x; v1 = sv.y; v2 = sv.z; v3 = sv.w;
            }
            int sb = q * 4;
            lds[(sb + 0) * 120 + ch] = v0;
            lds[(sb + 1) * 120 + ch] = v1;
            lds[(sb + 2) * 120 + ch] = v2;
            lds[(sb + 3) * 120 + ch] = v3;
        }
        __syncthreads();

        f32x16 acc[12];
        #pragma unroll
        for (int m = 0; m < 12; m++)
            #pragma unroll
            for (int r = 0; r < 16; r++) acc[m][r] = 0.f;

        const short* rec = &lds[px * 120];
        if (t == 0) {
            bf16x8 cB = *(const bf16x8*)(rec + kj * 8);
            #pragma unroll
            for (int mt = 0; mt < 12; mt++) {
                bf16x8 a = *(const bf16x8*)(EW + ((size_t)mt * 64 + lane) * 8);
                mfma_a(acc[mt], a, cB);
            }
        } else {
            bf16x8 cA[12], cB;
            cB = *(const bf16x8*)(rec + kj * 8);
            #pragma unroll
            for (int mt = 0; mt < 12; mt++)
                cA[mt] = *(const bf16x8*)(EW + ((size_t)mt * 64 + lane) * 8);
            #pragma unroll
            for (int k0 = 0; k0 < 7; k0++) {
                bf16x8 nA[12], nB;
                if (k0 < 6) {
                    nB = *(const bf16x8*)(rec + (k0 + 1) * 16 + kj * 8);
                    #pragma unroll
                    for (int mt = 0; mt < 12; mt++)
                        nA[mt] = *(const bf16x8*)(EW + ((size_t)((k0 + 1) * 12 + mt) * 64 + lane) * 8);
                }
                #pragma unroll
                for (int mt = 0; mt < 12; mt++) mfma_a(acc[mt], cA[mt], cB);
                if (k0 < 6) {
                    #pragma unroll
                    for (int mt = 0; mt < 12; mt++) cA[mt] = nA[mt];
                    cB = nB;
                }
            }
        }
        __syncthreads();

        // epilogue: LSTM pointwise, c in regs, h -> own LDS rec (+16 offset)
        #pragma unroll
        for (int dt = 0; dt < 3; dt++) {
            #pragma unroll
            for (int r = 0; r < 16; r++) {
                int row = (r & 3) + 8 * (r >> 2) + 4 * kj;
                int d = dt * 32 + row;
                float fg = sigmf_(acc[dt][r]     + ebf[d]);
                float ig = sigmf_(acc[3 + dt][r] + ebi[d]);
                float gg = tanhf_(acc[6 + dt][r] + ebc[d]);
                float og = sigmf_(acc[9 + dt][r] + ebo[d]);
                int ci = dt * 16 + r;
                float cn = fmaf(cre[ci], fg, ig * gg);
                cre[ci] = cn;
                lds[px * 120 + 16 + d] = f2bs(tanhf_(cn) * og);
            }
        }
        __syncthreads();
        if (t == T_ - 1) {
            // publish final enc h to hPA (pixel-major 96-ch records), coherent
            int px2 = tid >> 1, half = tid & 1;
            short* gdst = hPA + ((size_t)b * HW + pix0 + px2) * 96 + half * 48;
            const short* lsrc = &lds[px2 * 120 + 16 + half * 48];
            #pragma unroll
            for (int s2 = 0; s2 < 6; s2++)
                stB16(gdst + s2 * 8, *(const i32x4*)(lsrc + s2 * 8));
        }
    }
    // signal: enc h published (prog = 1)
    vm0();
    __syncthreads();
    if (tid == 0)
        __hip_atomic_store(&prog[blockIdx.x * 16], 1, __ATOMIC_RELAXED, __HIP_MEMORY_SCOPE_AGENT);

    // ================= decoder phase =====
    #pragma unroll 1
    for (int tt = 0; tt <= T_; tt++) {
        short* hR  = (tt & 1) ? hPB : hPA;    // h_{tt-1}
        short* hWr = (tt & 1) ? hPA : hPB;    // h_tt

        if (tt == 0) {
            // zero pass: edge slots + ch pads (disjoint from all staging)
            #pragma unroll 1
            for (int i = tid; i < 648; i += 256) {
                int addr_sh;
                if (i < 120) {
                    int r = i / 30, rem = i % 30;
                    int s = (rem / 15) * 65;
                    addr_sh = (r * 66 + s) * 120 + (rem % 15) * 8;
                } else {
                    int z = i - 120;
                    addr_sh = (z >> 1) * 120 + 104 + (z & 1) * 8;
                }
                *(i32x4*)(&lds[addr_sh]) = z4;
            }
        }
        // x staging FIRST (no neighbor dependency -> overlaps the wait)
        if (tt < T_) {
            #pragma unroll
            for (int it = 0; it < 2; it++) {
                int i = tid + it * 256;
                int ch = i & 7, q = (i >> 3) & 15, r = i >> 7;
                int y = y0 - 1 + r;
                short v0 = 0, v1 = 0, v2 = 0, v3 = 0;
                if ((unsigned)y < 64u) {
                    size_t base = ((size_t)(b * T_ + tt) * COUT + ch) * HW + y * 64 + q * 4;
                    if (f32) {
                        float4 f = *(const float4*)((const float*)xd + base);
                        v0 = f2bs(f.x); v1 = f2bs(f.y); v2 = f2bs(f.z); v3 = f2bs(f.w);
                    } else {
                        short4 sv = *(const short4*)((const short*)xd + base);
                        v0 = sv.x; v1 = sv.y; v2 = sv.z; v3 = sv.w;
                    }
                }
                int sb = r * 66 + 1 + q * 4;
                lds[(sb + 0) * 120 + ch] = v0;
                lds[(sb + 1) * 120 + ch] = v1;
                lds[(sb + 2) * 120 + ch] = v2;
                lds[(sb + 3) * 120 + ch] = v3;
            }
        }

        // neighbor sync: need h_{tt-1} of bands band+-1 published (prog>=tt+1)
        if (tid < 2) {
            int nb = band + (tid ? 1 : -1);
            if ((unsigned)nb < 32u)
                wait_prog(prog + (((nb << 3) | b) << 4), tt + 1);
        }
        __syncthreads();

        if (tt == 0) {
            // full h staging: 4 rows x 64 recs x 12 chunks (coherent loads)
            i32x4 tmp[12]; int ss2[12], jj2[12];
            #pragma unroll
            for (int i = 0; i < 12; i++) {
                int c2 = tid + i * 256;
                int s = c2 / 12, j = c2 - s * 12;
                ss2[i] = s; jj2[i] = j;
                int y = y0 - 1 + (s >> 6);
                if ((unsigned)y < 64u)
                    tmp[i] = ldB16(hR + ((size_t)b * HW + (size_t)y * 64 + (s & 63)) * 96 + j * 8);
                else tmp[i] = z4;
            }
            vm0();
            #pragma unroll
            for (int i = 0; i < 12; i++) {
                int s = ss2[i];
                *(i32x4*)(&lds[((s >> 6) * 66 + 1 + (s & 63)) * 120 + 8 + jj2[i] * 8]) = tmp[i];
            }
        } else {
            // halo staging only: rows y0-1 (slot-row 0) and y0+2 (slot-row 3)
            i32x4 tmp[6]; int ss2[6], jj2[6];
            #pragma unroll
            for (int i = 0; i < 6; i++) {
                int c2 = tid + i * 256;           // 0..1535
                int s = c2 / 12, j = c2 - s * 12; // s 0..127
                int hi = s >> 6;                  // 0 top, 1 bottom
                int y = hi ? (y0 + 2) : (y0 - 1);
                ss2[i] = hi * 3 * 66 + 1 + (s & 63);
                jj2[i] = j;
                if ((unsigned)y < 64u)
                    tmp[i] = ldB16(hR + ((size_t)b * HW + (size_t)y * 64 + (s & 63)) * 96 + j * 8);
                else tmp[i] = z4;
            }
            vm0();
            #pragma unroll
            for (int i = 0; i < 6; i++)
                *(i32x4*)(&lds[ss2[i] * 120 + 8 + jj2[i] * 8]) = tmp[i];
        }
        __syncthreads();

        const int rw = 1 + (wave >> 1);
        const int x0 = (wave & 1) * 32;
        const int ldA = (tt < T_) ? 1 : 0;

        f32x16 aF[9], aO[3], aOut;
        #pragma unroll
        for (int m = 0; m < 9; m++)
            #pragma unroll
            for (int r = 0; r < 16; r++) aF[m][r] = 0.f;
        #pragma unroll
        for (int m = 0; m < 3; m++)
            #pragma unroll
            for (int r = 0; r < 16; r++) aO[m][r] = 0.f;
        #pragma unroll
        for (int r = 0; r < 16; r++) aOut[r] = 0.f;

        // row base pointers per tap (dy = tap/3-1, dx = tap%3-1)
        // main tap loop, 1-deep prefetch pipeline across tap boundaries
        {
            bf16x8 cA[9], cK, cB;
            {
                const short* rec0 = &lds[((rw - 1) * 66 + x0 + n) * 120]; // tap0: dy=-1,dx=-1
                ldfragsD(cA, cK, cB, WtA + (size_t)lane * 8, K2A + (size_t)lane * 8,
                         rec0, 0, kj, ldA);
            }
            #pragma unroll 1
            for (int tap = 0; tap < 9; tap++) {
                int dy = tap / 3 - 1, dx = tap - (tap / 3) * 3 - 1;
                int tapN = (tap < 8) ? tap + 1 : 8;
                int dyN = tapN / 3 - 1, dxN = tapN - (tapN / 3) * 3 - 1;
                const short* rec  = &lds[((rw + dy)  * 66 + 1 + x0 + n + dx)  * 120];
                const short* recN = &lds[((rw + dyN) * 66 + 1 + x0 + n + dxN) * 120];
                const short* ab  = WtA + ((size_t)(tap  * 7) * 12 * 64 + lane) * 8;
                const short* abN = WtA + ((size_t)(tapN * 7) * 12 * 64 + lane) * 8;
                const short* kb  = K2A + ((size_t)(tap  * 7) * 64 + lane) * 8;
                const short* kbN = K2A + ((size_t)(tapN * 7) * 64 + lane) * 8;
                #pragma unroll
                for (int k0 = 0; k0 < 7; k0++) {
                    bf16x8 nA[9], nK, nB;
                    if (k0 < 6) ldfragsD(nA, nK, nB, ab, kb, rec, k0 + 1, kj, ldA);
                    else        ldfragsD(nA, nK, nB, abN, kbN, recN, 0, kj, ldA);
                    if (tt < T_) {
                        #pragma unroll
                        for (int mt = 0; mt < 9; mt++) mfma_a(aF[mt], cA[mt], cB);
                    }
                    if (tt > 0) mfma_a(aOut, cK, cB);
                    #pragma unroll
                    for (int q = 0; q < 9; q++) cA[q] = nA[q];
                    cK = nK; cB = nB;
                }
            }
        }
        // o gate: center tap only, m-tiles 9..11, same prefetch pattern
        if (tt < T_) {
            const short* rec = &lds[(rw * 66 + 1 + x0 + n) * 120];
            const short* ab = WtA + ((size_t)(4 * 7) * 12 * 64 + lane) * 8 + 9 * 512;
            bf16x8 cA[3], cB;
            cB = *(const bf16x8*)(rec + kj * 8);
            #pragma unroll
            for (int mt = 0; mt < 3; mt++)
                cA[mt] = *(const bf16x8*)(ab + (size_t)mt * 512);
            #pragma unroll
            for (int k0 = 0; k0 < 7; k0++) {
                bf16x8 nA[3], nB;
                if (k0 < 6) {
                    const short* a0 = ab + (size_t)(k0 + 1) * 12 * 64 * 8;
                    nB = *(const bf16x8*)(rec + (k0 + 1) * 16 + kj * 8);
                    #pragma unroll
                    for (int mt = 0; mt < 3; mt++)
                        nA[mt] = *(const bf16x8*)(a0 + (size_t)mt * 512);
                }
                #pragma unroll
                for (int mt = 0; mt < 3; mt++) mfma_a(aO[mt], cA[mt], cB);
                if (k0 < 6) {
                    #pragma unroll
                    for (int mt = 0; mt < 3; mt++) cA[mt] = nA[mt];
                    cB = nB;
                }
            }
        }
        __syncthreads();

        // fused out store for step tt-1 (C rows 0..7 = out channels)
        if (tt > 0) {
            #pragma unroll
            for (int r = 0; r < 4; r++) {
                int o = r + 4 * kj;
                float v = aOut[r] + b2[o];
                size_t oadr = ((size_t)(b * T_ + (tt - 1)) * COUT + o) * HW + pg;
                if (f32) ((float*)out)[oadr] = v;
                else     ((bf16*)out)[oadr] = __float2bfloat16(v);
            }
        }

        if (tt < T_) {
            // epilogue: LSTM pointwise, c in regs, h -> own staged recs
            #pragma unroll
            for (int dt = 0; dt < 3; dt++) {
                #pragma unroll
                for (int r = 0; r < 16; r++) {
                    int row = (r & 3) + 8 * (r >> 2) + 4 * kj;
                    int d = dt * 32 + row;
                    float fg = sigmf_(aF[dt][r]     + dbf[d]);
                    float ig = sigmf_(aF[3 + dt][r] + dbi[d]);
                    float gg = tanhf_(aF[6 + dt][r] + dbc[d]);
                    float og = sigmf_(aO[dt][r]     + dbo[d]);
                    int ci = dt * 16 + r;
                    float cn = fmaf(cre[ci], fg, ig * gg);
                    cre[ci] = cn;
                    float hv = tanhf_(cn) * og;
                    lds[((1 + (px >> 6)) * 66 + 1 + (px & 63)) * 120 + 8 + d] = f2bs(hv);
                }
            }
            __syncthreads();
            // publish own 2 rows to hWr (pixel-major records), coherent
            int px2 = tid >> 1, half = tid & 1;
            short* gdst = hWr + ((size_t)b * HW + pix0 + px2) * 96 + half * 48;
            const short* lsrc = &lds[((1 + (px2 >> 6)) * 66 + 1 + (px2 & 63)) * 120 + 8 + half * 48];
            #pragma unroll
            for (int s2 = 0; s2 < 6; s2++)
                stB16(gdst + s2 * 8, *(const i32x4*)(lsrc + s2 * 8));
            // signal: h_tt published (prog = tt+2)
            vm0();
            __syncthreads();
            if (tid == 0)
                __hip_atomic_store(&prog[blockIdx.x * 16], tt + 2,
                                   __ATOMIC_RELAXED, __HIP_MEMORY_SCOPE_AGENT);
        }
        // no signal after the final out-only pass (tt == T_)
    }
}

// ---------------------------------------------------------------------------
extern "C" void kernel_launch(void* const* d_in, const int* in_sizes, int n_in,
                              void* d_out, int out_size, void* d_ws, size_t ws_size,
                              hipStream_t stream)
{
    const void* enc_in = d_in[0];
    const void* dec_in = d_in[1];
    const void* eWf = d_in[2];  const void* ebf_ = d_in[3];
    const void* eWi = d_in[4];  const void* ebi_ = d_in[5];
    const void* eWc = d_in[6];  const void* ebc_ = d_in[7];
    const void* eWo = d_in[8];  const void* ebo_ = d_in[9];
    const void* dKf = d_in[10]; const void* dbf_ = d_in[11];
    const void* dKi = d_in[12]; const void* dbi_ = d_in[13];
    const void* dKc = d_in[14]; const void* dbc_ = d_in[15];
    const void* dWo = d_in[16]; const void* dbo_ = d_in[17];
    const void* oK  = d_in[18]; const void* obv = d_in[19];
    const void* lW  = d_in[20]; const void* lb  = d_in[21];

    int* flag = (int*)d_ws;
    int* prog = (int*)d_ws + 16;             // 256 slots x 16 ints (64B stride)
    float* ws = (float*)d_ws + 16 + 4096;

    const int S = B_ * HD * HW;              // 3,145,728 state elems
    short* hPA = (short*)ws;                 // S shorts (pixel-major h)
    short* hPB = (short*)(ws + S / 2);       // S shorts
    float* biases = ws + S;                  // 8 x 96 fp32
    float* b2   = biases + 768;              // 16
    short* WtA  = (short*)(b2 + 16);                  // 387,072 shorts
    short* EW   = (short*)(b2 + 16 + 193536);         // 43,008 shorts
    short* K2A  = (short*)(b2 + 16 + 193536 + 21504); // 32,256 shorts

    setup_k<<<dim3(231), dim3(256), 0, stream>>>(
        eWf, ebf_, eWi, ebi_, eWc, ebc_, eWo, ebo_,
        dKf, dbf_, dKi, dbi_, dKc, dbc_, dWo, dbo_,
        oK, obv, lW, lb,
        biases, b2, EW, WtA, K2A, flag, prog);

    net_k<<<dim3(256), dim3(256), 0, stream>>>(
        enc_in, dec_in, hPA, hPB, d_out,
        EW, WtA, K2A,
        biases + 0, biases + 96, biases + 192, biases + 288,
        biases + 384, biases + 480, biases + 576, biases + 672,
        b2, flag, prog);
}